// Round 5
// baseline (808.747 us; speedup 1.0000x reference)
//
#include <hip/hip_runtime.h>
#include <cstdint>
#include <cstddef>

typedef unsigned short u16;
typedef u16 u16x8 __attribute__((ext_vector_type(8)));
typedef __bf16 bf16x8 __attribute__((ext_vector_type(8)));
typedef float f32x4 __attribute__((ext_vector_type(4)));

#define B_ROWS 16384
#define DIM 1024
#define ORDH 512
#define NEXP 7
#define NFUSE 2560   // 512 (ord) + 1024 (res) + 1024 (adapter)
#define NMEGA 3584   // NFUSE + 1024 (cls)

__device__ __forceinline__ u16 f2bf(float f) {
  unsigned u = __builtin_bit_cast(unsigned, f);
  u += 0x7FFFu + ((u >> 16) & 1u);  // RNE
  return (u16)(u >> 16);
}
__device__ __forceinline__ float bf2f(u16 h) {
  return __builtin_bit_cast(float, ((unsigned)h) << 16);
}

// async global->LDS, 16B per lane (global_load_lds_dwordx4)
typedef __attribute__((address_space(1))) const void gas_void;
typedef __attribute__((address_space(3))) void las_void;
__device__ __forceinline__ void gload16(const void* g, void* l) {
  __builtin_amdgcn_global_load_lds((gas_void*)g, (las_void*)l, 16, 0, 0);
}

// x fp32 -> bf16 hi + lo; zeroes gcnt/cursor and the head accumulators.
__global__ __launch_bounds__(256) void convert_x_kernel(
    const float4* __restrict__ x, ushort4* __restrict__ xh,
    ushort4* __restrict__ xl, int* __restrict__ gcnt, int* __restrict__ cursor,
    float* __restrict__ zacc) {
  if (blockIdx.x == 0 && threadIdx.x < 2 * NEXP) {
    if (threadIdx.x < NEXP) gcnt[threadIdx.x] = 0;
    else cursor[threadIdx.x - NEXP] = 0;
  }
  const int z = blockIdx.x * 256 + threadIdx.x;
  if (z < 17 * B_ROWS) zacc[z] = 0.f;  // ord(6)+res(1)+cls(7)+dl(3) per row
  const int i = z;
  float4 v = x[i];
  ushort4 h, l;
  h.x = f2bf(v.x); l.x = f2bf(v.x - bf2f(h.x));
  h.y = f2bf(v.y); l.y = f2bf(v.y - bf2f(h.y));
  h.z = f2bf(v.z); l.z = f2bf(v.z - bf2f(h.z));
  h.w = f2bf(v.w); l.w = f2bf(v.w - bf2f(h.w));
  xh[i] = h; xl[i] = l;
}

// ALL weight transposes in one launch. W [K][N] f32 -> WT [N][K] bf16.
// flat grid decode: Wc1(1024) | Wo1(512) | Wr1(1024) | Wa(1024) |
//                   We1(7x1024) | We2(7x1024)  = 17920 blocks
__global__ __launch_bounds__(256) void transpose_all_kernel(
    const float* __restrict__ Wc1, u16* __restrict__ Tc1h, u16* __restrict__ Tc1l,
    const float* __restrict__ Wo1, u16* __restrict__ To1,
    const float* __restrict__ Wr1, u16* __restrict__ Tr1,
    const float* __restrict__ Wa,  u16* __restrict__ Ta,
    const float* __restrict__ We1, u16* __restrict__ Te1,
    const float* __restrict__ We2, u16* __restrict__ Te2) {
  __shared__ float tile[32][33];
  int bid = blockIdx.x;
  const float* W; u16* H; u16* L = nullptr;
  int N = 1024, bx, by;
  size_t zoff = 0;
  if (bid < 1024)      { W = Wc1; H = Tc1h; L = Tc1l; bx = bid & 31; by = bid >> 5; }
  else if (bid < 1536) { bid -= 1024; W = Wo1; H = To1; N = 512; bx = bid & 15; by = bid >> 4; }
  else if (bid < 2560) { bid -= 1536; W = Wr1; H = Tr1; bx = bid & 31; by = bid >> 5; }
  else if (bid < 3584) { bid -= 2560; W = Wa; H = Ta; bx = bid & 31; by = bid >> 5; }
  else if (bid < 10752){ bid -= 3584; W = We1; H = Te1;
                         zoff = (size_t)(bid >> 10) * DIM * DIM; bid &= 1023;
                         bx = bid & 31; by = bid >> 5; }
  else                 { bid -= 10752; W = We2; H = Te2;
                         zoff = (size_t)(bid >> 10) * DIM * DIM; bid &= 1023;
                         bx = bid & 31; by = bid >> 5; }
  const int K = 1024;
  const int bk = by * 32, bn = bx * 32;
  const int tx = threadIdx.x & 31, ty = threadIdx.x >> 5;  // 32 x 8
#pragma unroll
  for (int r = 0; r < 32; r += 8)
    tile[ty + r][tx] = W[zoff + (size_t)(bk + ty + r) * N + (bn + tx)];
  __syncthreads();
#pragma unroll
  for (int r = 0; r < 32; r += 8) {
    const float v = tile[tx][ty + r];
    const size_t o = zoff + (size_t)(bn + ty + r) * K + (bk + tx);
    const u16 h = f2bf(v);
    H[o] = h;
    if (L) L[o] = f2bf(v - bf2f(h));
  }
}

// ---------------------------------------------------------------------------
// GEMM core (R2 structure, proven ~900 TF @K=1024): 128x128x64 tile, 4 waves,
// 4x4 mfma 16x16x32. global_load_lds width-16 into LINEAR LDS; T2 both-sides
// swizzle; double-buffer 2x32KB; counted s_waitcnt vmcnt(8), never drained
// in the main loop. B pointers are pre-offset by their row; n0 arg = 0.
// ---------------------------------------------------------------------------
__device__ __forceinline__ void gemm_loop(
    const u16* __restrict__ aP0, const u16* __restrict__ bP0,
    const u16* __restrict__ aP1, const u16* __restrict__ bP1,
    const u16* __restrict__ aP2, const u16* __restrict__ bP2,
    int npass, int K, int m0, u16* SM, int tid, f32x4 (&acc)[4][4]) {
  const int lane = tid & 63;
  const int w = tid >> 6;
  const int wm = w >> 1, wn = w & 1;
  const int sRow = tid >> 3, sSlot = tid & 7;  // 32 rows x 8 chunks(16B)
  const int ldsOff = sRow * 64 + sSlot * 8;
  const size_t aOff = (size_t)(m0 + sRow) * K + ((sSlot ^ (sRow & 7)) * 8);
  const size_t bOff = (size_t)sRow * K + ((sSlot ^ (sRow & 7)) * 8);
  const u16* aCur = aP0 + aOff;
  const u16* bCur = bP0 + bOff;
  int sp = 0, sk = 0;  // next tile to stage
  auto stageNext = [&](int b) {
    u16* d = SM + b * 16384 + ldsOff;
    const u16* as = aCur + sk;
    const u16* bs = bCur + sk;
#pragma unroll
    for (int r = 0; r < 4; ++r) {
      gload16(as + (size_t)(r * 32) * K, d + r * 32 * 64);
      gload16(bs + (size_t)(r * 32) * K, d + 8192 + r * 32 * 64);
    }
    sk += 64;
    if (sk == K) {
      sk = 0; ++sp;
      if (sp == 1) { aCur = aP1 + aOff; bCur = bP1 + bOff; }
      else         { aCur = aP2 + aOff; bCur = bP2 + bOff; }
    }
  };

  const int ntiles = npass * (K >> 6);
  stageNext(0);
  int cur = 0;
  for (int ti = 0; ti < ntiles; ++ti) {
    if (ti + 1 < ntiles) {
      stageNext(cur ^ 1);
      // wait for CURRENT buffer's 8 loads (keep the 8 just-issued in flight)
      asm volatile("s_waitcnt vmcnt(8)\n\ts_barrier" ::: "memory");
    } else {
      asm volatile("s_waitcnt vmcnt(0)\n\ts_barrier" ::: "memory");
    }
    const u16* As = SM + cur * 16384;
    const u16* Bs = As + 8192;
#pragma unroll
    for (int s = 0; s < 2; ++s) {
      const int cAx = s * 4 + (lane >> 4);
      const int colO = (cAx ^ (lane & 7)) * 8;  // T2 swizzled read chunk
      bf16x8 af[4], bfr[4];
#pragma unroll
      for (int t = 0; t < 4; ++t) {
        const int rowA = wm * 64 + t * 16 + (lane & 15);
        af[t] = __builtin_bit_cast(bf16x8, *(const u16x8*)&As[rowA * 64 + colO]);
        const int rowB = wn * 64 + t * 16 + (lane & 15);
        bfr[t] = __builtin_bit_cast(bf16x8, *(const u16x8*)&Bs[rowB * 64 + colO]);
      }
#pragma unroll
      for (int mt = 0; mt < 4; ++mt)
#pragma unroll
        for (int nt = 0; nt < 4; ++nt)
          acc[mt][nt] = __builtin_amdgcn_mfma_f32_16x16x32_bf16(
              af[mt], bfr[nt], acc[mt][nt], 0, 0, 0);
    }
    asm volatile("s_barrier" ::: "memory");
    cur ^= 1;
  }
}

// ---------------------------------------------------------------------------
// mega GEMM: 28 col-tiles x 128 row-tiles, one dispatch.
//   cols [0,512):      ord hidden  -> fused partial dot Wo2 -> ordacc atomics
//   cols [512,1536):   res hidden  -> fused partial dot Wr2 -> resacc atomics
//   cols [1536,2560):  adapter     -> DF bf16 store (experts need it)
//   cols [2560,3584):  cls hidden 3-pass hi/lo -> partial dot Wc2 -> clsacc
// Head hiddens are never materialized (saves ~290MB HBM round-trips).
// ---------------------------------------------------------------------------
__global__ __launch_bounds__(256, 2) void mega_gemm_kernel(
    const u16* __restrict__ xh, const u16* __restrict__ xl,
    const u16* __restrict__ Tall, const u16* __restrict__ Tc1h,
    const u16* __restrict__ Tc1l,
    const float* __restrict__ bo1, const float* __restrict__ br1,
    const float* __restrict__ ba, const float* __restrict__ bc1,
    const float* __restrict__ Wo2, const float* __restrict__ Wr2,
    const float* __restrict__ Wc2,
    float* __restrict__ ordacc, float* __restrict__ resacc,
    float* __restrict__ clsacc, u16* __restrict__ DF) {
  __shared__ __attribute__((aligned(16))) u16 SM[4 * 128 * 64];
  const int tid = threadIdx.x;
  const int lane = tid & 63;
  const int w = tid >> 6;
  const int wm = w >> 1, wn = w & 1;
  // XCD-aware bijective swizzle (nwg = 3584, % 8 == 0)
  const unsigned nwg = gridDim.x * gridDim.y;
  const unsigned wgid = blockIdx.y * gridDim.x + blockIdx.x;
  const unsigned swz = (wgid & 7u) * (nwg >> 3) + (wgid >> 3);
  const int m0 = (int)(swz / gridDim.x) * 128;
  const int n0 = (int)(swz % gridDim.x) * 128;

  f32x4 acc[4][4] = {};
  if (n0 < NFUSE) {
    const u16* b = Tall + (size_t)n0 * DIM;
    gemm_loop(xh, b, xh, b, xh, b, 1, DIM, m0, SM, tid, acc);
  } else {
    const u16* bh = Tc1h + (size_t)(n0 - NFUSE) * DIM;
    const u16* bl = Tc1l + (size_t)(n0 - NFUSE) * DIM;
    gemm_loop(xh, bh, xh, bl, xl, bh, 3, DIM, m0, SM, tid, acc);
  }

  const int q = lane >> 4, cl = lane & 15;
  if (n0 < ORDH) {
    // ord head: 6-wide partial dot, reduce over 16-lane col group
#pragma unroll
    for (int mt = 0; mt < 4; ++mt)
#pragma unroll
      for (int i = 0; i < 4; ++i) {
        const int row = m0 + wm * 64 + mt * 16 + q * 4 + i;
        float s[6] = {0, 0, 0, 0, 0, 0};
#pragma unroll
        for (int nt = 0; nt < 4; ++nt) {
          const int col = n0 + wn * 64 + nt * 16 + cl;
          float v = acc[mt][nt][i] + bo1[col];
          v = v > 0.f ? v : 0.f;
          const float* wr = Wo2 + col * 6;
#pragma unroll
          for (int n = 0; n < 6; ++n) s[n] += v * wr[n];
        }
#pragma unroll
        for (int n = 0; n < 6; ++n) {
          s[n] += __shfl_xor(s[n], 1);
          s[n] += __shfl_xor(s[n], 2);
          s[n] += __shfl_xor(s[n], 4);
          s[n] += __shfl_xor(s[n], 8);
        }
        if (cl == 0)
#pragma unroll
          for (int n = 0; n < 6; ++n) atomicAdd(&ordacc[row * 6 + n], s[n]);
      }
  } else if (n0 < ORDH + DIM) {
    // res head: scalar partial dot
#pragma unroll
    for (int mt = 0; mt < 4; ++mt)
#pragma unroll
      for (int i = 0; i < 4; ++i) {
        const int row = m0 + wm * 64 + mt * 16 + q * 4 + i;
        float s = 0.f;
#pragma unroll
        for (int nt = 0; nt < 4; ++nt) {
          const int col = n0 - ORDH + wn * 64 + nt * 16 + cl;  // hidden dim idx
          float v = acc[mt][nt][i] + br1[col];
          v = v > 0.f ? v : 0.f;
          s += v * Wr2[col];
        }
        s += __shfl_xor(s, 1);
        s += __shfl_xor(s, 2);
        s += __shfl_xor(s, 4);
        s += __shfl_xor(s, 8);
        if (cl == 0) atomicAdd(&resacc[row], s);
      }
  } else if (n0 < NFUSE) {
    // adapter: materialize DF (experts consume it)
#pragma unroll
    for (int nt = 0; nt < 4; ++nt) {
      const int col = n0 - (ORDH + DIM) + wn * 64 + nt * 16 + cl;
      const float bv = ba[col];
#pragma unroll
      for (int mt = 0; mt < 4; ++mt)
#pragma unroll
        for (int i = 0; i < 4; ++i) {
          const int row = m0 + wm * 64 + mt * 16 + q * 4 + i;
          float v = acc[mt][nt][i] + bv;
          v = v > 0.f ? v : 0.f;
          DF[(size_t)row * DIM + col] = f2bf(v);
        }
    }
  } else {
    // cls head: 7-wide partial dot
#pragma unroll
    for (int mt = 0; mt < 4; ++mt)
#pragma unroll
      for (int i = 0; i < 4; ++i) {
        const int row = m0 + wm * 64 + mt * 16 + q * 4 + i;
        float s[7] = {0, 0, 0, 0, 0, 0, 0};
#pragma unroll
        for (int nt = 0; nt < 4; ++nt) {
          const int col = n0 - NFUSE + wn * 64 + nt * 16 + cl;  // hidden dim idx
          float v = acc[mt][nt][i] + bc1[col];
          v = v > 0.f ? v : 0.f;
          const float* wr = Wc2 + col * 7;
#pragma unroll
          for (int n = 0; n < 7; ++n) s[n] += v * wr[n];
        }
#pragma unroll
        for (int n = 0; n < 7; ++n) {
          s[n] += __shfl_xor(s[n], 1);
          s[n] += __shfl_xor(s[n], 2);
          s[n] += __shfl_xor(s[n], 4);
          s[n] += __shfl_xor(s[n], 8);
        }
        if (cl == 0)
#pragma unroll
          for (int n = 0; n < 7; ++n) atomicAdd(&clsacc[row * 7 + n], s[n]);
      }
  }
}

// expert1: rows [base+t0, base+cnt[e]), A gathered through perm; writes H1p.
__global__ __launch_bounds__(256, 2) void mgemm_expert1_kernel(
    const u16* __restrict__ Abuf, const u16* __restrict__ Wall,
    const float* __restrict__ biasAll, const int* __restrict__ cnt,
    const int* __restrict__ perm, u16* __restrict__ outH) {
  __shared__ __attribute__((aligned(16))) u16 SM[4 * 128 * 64];
  const int e = blockIdx.z;
  const int myCnt = cnt[e];
  const int t0 = blockIdx.y * 128;
  if (t0 >= myCnt) return;
  int base = 0;
  for (int t = 0; t < NEXP; ++t) base += (t < e) ? cnt[t] : 0;
  const int m0 = base + t0;
  const int mEnd = base + myCnt;
  const u16* Bp = Wall + (size_t)e * DIM * DIM;
  const float* bias = biasAll + (size_t)e * DIM;

  const int tid = threadIdx.x;
  const int lane = tid & 63;
  const int w = tid >> 6;
  const int wm = w >> 1, wn = w & 1;
  const int n0 = blockIdx.x * 128;
  const int sRow = tid >> 3, sSlot = tid & 7;
  const int ldsOff = sRow * 64 + sSlot * 8;
  const int swzC = (sSlot ^ (sRow & 7)) * 8;

  const u16* aSrc[4];
#pragma unroll
  for (int r = 0; r < 4; ++r) {
    int ar = m0 + r * 32 + sRow;
    if (ar > B_ROWS - 1) ar = B_ROWS - 1;
    aSrc[r] = Abuf + (size_t)perm[ar] * DIM + swzC;
  }
  const u16* bSrc = Bp + (size_t)(n0 + sRow) * DIM + swzC;

  int sk = 0;
  auto stageNext = [&](int b) {
    u16* d = SM + b * 16384 + ldsOff;
#pragma unroll
    for (int r = 0; r < 4; ++r)
      gload16(aSrc[r] + sk, d + r * 32 * 64);
#pragma unroll
    for (int r = 0; r < 4; ++r)
      gload16(bSrc + (size_t)(r * 32) * DIM + sk, d + 8192 + r * 32 * 64);
    sk += 64;
  };

  f32x4 acc[4][4] = {};
  const int ntiles = DIM >> 6;
  stageNext(0);
  int cur = 0;
  for (int ti = 0; ti < ntiles; ++ti) {
    if (ti + 1 < ntiles) {
      stageNext(cur ^ 1);
      asm volatile("s_waitcnt vmcnt(8)\n\ts_barrier" ::: "memory");
    } else {
      asm volatile("s_waitcnt vmcnt(0)\n\ts_barrier" ::: "memory");
    }
    const u16* As = SM + cur * 16384;
    const u16* Bs = As + 8192;
#pragma unroll
    for (int s = 0; s < 2; ++s) {
      const int cAx = s * 4 + (lane >> 4);
      const int colO = (cAx ^ (lane & 7)) * 8;
      bf16x8 af[4], bfr[4];
#pragma unroll
      for (int t = 0; t < 4; ++t) {
        const int rowA = wm * 64 + t * 16 + (lane & 15);
        af[t] = __builtin_bit_cast(bf16x8, *(const u16x8*)&As[rowA * 64 + colO]);
        const int rowB = wn * 64 + t * 16 + (lane & 15);
        bfr[t] = __builtin_bit_cast(bf16x8, *(const u16x8*)&Bs[rowB * 64 + colO]);
      }
#pragma unroll
      for (int mt = 0; mt < 4; ++mt)
#pragma unroll
        for (int nt = 0; nt < 4; ++nt)
          acc[mt][nt] = __builtin_amdgcn_mfma_f32_16x16x32_bf16(
              af[mt], bfr[nt], acc[mt][nt], 0, 0, 0);
    }
    asm volatile("s_barrier" ::: "memory");
    cur ^= 1;
  }

  const int q = lane >> 4, cl = lane & 15;
#pragma unroll
  for (int nt = 0; nt < 4; ++nt) {
    const int col = n0 + wn * 64 + nt * 16 + cl;
    const float bv = bias[col];
#pragma unroll
    for (int mt = 0; mt < 4; ++mt) {
#pragma unroll
      for (int i = 0; i < 4; ++i) {
        const int row = m0 + wm * 64 + mt * 16 + q * 4 + i;
        if (row < mEnd) {
          float v = acc[mt][nt][i] + bv;
          v = v > 0.f ? v : 0.f;
          outH[(size_t)row * DIM + col] = f2bf(v);
        }
      }
    }
  }
}

// expert2: same GEMM; epilogue fuses head_dl — relu(h2) partial dot We3[e]
// (3-wide) -> dlacc atomics. H2 never materialized.
__global__ __launch_bounds__(256, 2) void mgemm_expert2_kernel(
    const u16* __restrict__ Abuf, const u16* __restrict__ Wall,
    const float* __restrict__ biasAll, const int* __restrict__ cnt,
    const float* __restrict__ We3, float* __restrict__ dlacc) {
  __shared__ __attribute__((aligned(16))) u16 SM[4 * 128 * 64];
  const int e = blockIdx.z;
  const int myCnt = cnt[e];
  const int t0 = blockIdx.y * 128;
  if (t0 >= myCnt) return;
  int base = 0;
  for (int t = 0; t < NEXP; ++t) base += (t < e) ? cnt[t] : 0;
  const int m0 = base + t0;
  const int mEnd = base + myCnt;
  const u16* Bp = Wall + (size_t)e * DIM * DIM;
  const float* bias = biasAll + (size_t)e * DIM;
  const float* W3 = We3 + (size_t)e * DIM * 3;

  const int tid = threadIdx.x;
  const int lane = tid & 63;
  const int w = tid >> 6;
  const int wm = w >> 1, wn = w & 1;
  const int n0 = blockIdx.x * 128;
  const int sRow = tid >> 3, sSlot = tid & 7;
  const int ldsOff = sRow * 64 + sSlot * 8;
  const int swzC = (sSlot ^ (sRow & 7)) * 8;

  const u16* aSrc[4];
#pragma unroll
  for (int r = 0; r < 4; ++r) {
    int ar = m0 + r * 32 + sRow;
    if (ar > B_ROWS - 1) ar = B_ROWS - 1;
    aSrc[r] = Abuf + (size_t)ar * DIM + swzC;
  }
  const u16* bSrc = Bp + (size_t)(n0 + sRow) * DIM + swzC;

  int sk = 0;
  auto stageNext = [&](int b) {
    u16* d = SM + b * 16384 + ldsOff;
#pragma unroll
    for (int r = 0; r < 4; ++r)
      gload16(aSrc[r] + sk, d + r * 32 * 64);
#pragma unroll
    for (int r = 0; r < 4; ++r)
      gload16(bSrc + (size_t)(r * 32) * DIM + sk, d + 8192 + r * 32 * 64);
    sk += 64;
  };

  f32x4 acc[4][4] = {};
  const int ntiles = DIM >> 6;
  stageNext(0);
  int cur = 0;
  for (int ti = 0; ti < ntiles; ++ti) {
    if (ti + 1 < ntiles) {
      stageNext(cur ^ 1);
      asm volatile("s_waitcnt vmcnt(8)\n\ts_barrier" ::: "memory");
    } else {
      asm volatile("s_waitcnt vmcnt(0)\n\ts_barrier" ::: "memory");
    }
    const u16* As = SM + cur * 16384;
    const u16* Bs = As + 8192;
#pragma unroll
    for (int s = 0; s < 2; ++s) {
      const int cAx = s * 4 + (lane >> 4);
      const int colO = (cAx ^ (lane & 7)) * 8;
      bf16x8 af[4], bfr[4];
#pragma unroll
      for (int t = 0; t < 4; ++t) {
        const int rowA = wm * 64 + t * 16 + (lane & 15);
        af[t] = __builtin_bit_cast(bf16x8, *(const u16x8*)&As[rowA * 64 + colO]);
        const int rowB = wn * 64 + t * 16 + (lane & 15);
        bfr[t] = __builtin_bit_cast(bf16x8, *(const u16x8*)&Bs[rowB * 64 + colO]);
      }
#pragma unroll
      for (int mt = 0; mt < 4; ++mt)
#pragma unroll
        for (int nt = 0; nt < 4; ++nt)
          acc[mt][nt] = __builtin_amdgcn_mfma_f32_16x16x32_bf16(
              af[mt], bfr[nt], acc[mt][nt], 0, 0, 0);
    }
    asm volatile("s_barrier" ::: "memory");
    cur ^= 1;
  }

  const int q = lane >> 4, cl = lane & 15;
#pragma unroll
  for (int mt = 0; mt < 4; ++mt)
#pragma unroll
    for (int i = 0; i < 4; ++i) {
      const int row = m0 + wm * 64 + mt * 16 + q * 4 + i;
      float s0 = 0.f, s1 = 0.f, s2 = 0.f;
#pragma unroll
      for (int nt = 0; nt < 4; ++nt) {
        const int col = n0 + wn * 64 + nt * 16 + cl;
        float v = acc[mt][nt][i] + bias[col];
        v = v > 0.f ? v : 0.f;
        const float* wr = W3 + col * 3;
        s0 += v * wr[0]; s1 += v * wr[1]; s2 += v * wr[2];
      }
      s0 += __shfl_xor(s0, 1); s0 += __shfl_xor(s0, 2);
      s0 += __shfl_xor(s0, 4); s0 += __shfl_xor(s0, 8);
      s1 += __shfl_xor(s1, 1); s1 += __shfl_xor(s1, 2);
      s1 += __shfl_xor(s1, 4); s1 += __shfl_xor(s1, 8);
      s2 += __shfl_xor(s2, 1); s2 += __shfl_xor(s2, 2);
      s2 += __shfl_xor(s2, 4); s2 += __shfl_xor(s2, 8);
      if (cl == 0 && row < mEnd) {
        atomicAdd(&dlacc[row * 3 + 0], s0);
        atomicAdd(&dlacc[row * 3 + 1], s1);
        atomicAdd(&dlacc[row * 3 + 2], s2);
      }
    }
}

// ---------------------------------------------------------------------------
// finalize: one thread per row. ord/res/cls outputs + softmax/argmax/routing.
// ---------------------------------------------------------------------------
__global__ __launch_bounds__(256) void finalize_cls_kernel(
    const float* __restrict__ ordacc, const float* __restrict__ bo2,
    const float* __restrict__ resacc, const float* __restrict__ br2,
    const float* __restrict__ clsacc, const float* __restrict__ bc2,
    float* __restrict__ out, int* __restrict__ size_idx, int* __restrict__ gcnt) {
  __shared__ int lcnt[NEXP];
  const int tid = threadIdx.x;
  if (tid < NEXP) lcnt[tid] = 0;
  __syncthreads();
  const int r = blockIdx.x * 256 + tid;
  float* orow = out + (size_t)r * 24;
#pragma unroll
  for (int n = 0; n < 6; ++n) orow[7 + n] = ordacc[r * 6 + n] + bo2[n];
  const float resv = 0.35f * tanhf(resacc[r] + br2[0]);
  float lg[7], pb[7];
  float m = -1e30f;
  int ai = 0;
#pragma unroll
  for (int n = 0; n < 7; ++n) {
    lg[n] = clsacc[r * 7 + n] + bc2[n];
    if (lg[n] > m) { m = lg[n]; ai = n; }  // first max == np.argmax
  }
  float es = 0.f;
#pragma unroll
  for (int n = 0; n < 7; ++n) { pb[n] = expf(lg[n] - m); es += pb[n]; }
  const float inv = 1.f / es;
  float expect = 0.f;
#pragma unroll
  for (int n = 0; n < 7; ++n) { pb[n] *= inv; expect += pb[n] * (n * (1.f / 6.f)); }
  float reg = expect + resv;
  reg = fminf(fmaxf(reg, 0.f), 1.f);
#pragma unroll
  for (int n = 0; n < 7; ++n) orow[n] = lg[n];
  orow[13] = reg;
#pragma unroll
  for (int n = 0; n < 7; ++n) orow[14 + n] = pb[n];
  size_idx[r] = ai;
  atomicAdd(&lcnt[ai], 1);
  __syncthreads();
  if (tid < NEXP && lcnt[tid] > 0) atomicAdd(&gcnt[tid], lcnt[tid]);
}

// scatter: off computed locally from final gcnt; cursor pre-zeroed.
__global__ __launch_bounds__(256) void scatter_kernel(
    const int* __restrict__ size_idx, const int* __restrict__ gcnt,
    int* __restrict__ cursor, int* __restrict__ perm) {
  __shared__ int lcnt[NEXP];
  __shared__ int lbase[NEXP];
  const int tid = threadIdx.x;
  if (tid < NEXP) lcnt[tid] = 0;
  __syncthreads();
  const int r = blockIdx.x * 256 + tid;
  const int e = size_idx[r];
  const int lp = atomicAdd(&lcnt[e], 1);
  __syncthreads();
  if (tid < NEXP && lcnt[tid] > 0) {
    int off = 0;
    for (int t = 0; t < tid; ++t) off += gcnt[t];
    lbase[tid] = off + atomicAdd(&cursor[tid], lcnt[tid]);
  }
  __syncthreads();
  perm[lbase[e] + lp] = r;
}

__global__ __launch_bounds__(256) void finalize_dl_kernel(
    const float* __restrict__ dlacc, const float* __restrict__ be3,
    const int* __restrict__ gcnt, const int* __restrict__ perm,
    float* __restrict__ out) {
  const int i = blockIdx.x * 256 + threadIdx.x;
  int e = 0, a = 0;
#pragma unroll
  for (int t = 0; t < NEXP - 1; ++t) {
    a += gcnt[t];
    if (i >= a) e = t + 1;
  }
  const int r = perm[i];
  float* orow = out + (size_t)r * 24;
#pragma unroll
  for (int c = 0; c < 3; ++c) orow[21 + c] = dlacc[i * 3 + c] + be3[e * 3 + c];
}

// ---------------------------------------------------------------------------
extern "C" void kernel_launch(void* const* d_in, const int* in_sizes, int n_in,
                              void* d_out, int out_size, void* d_ws, size_t ws_size,
                              hipStream_t stream) {
  (void)in_sizes; (void)n_in; (void)out_size; (void)ws_size;
  const float* x   = (const float*)d_in[0];
  const float* Wc1 = (const float*)d_in[1];
  const float* bc1 = (const float*)d_in[2];
  const float* Wc2 = (const float*)d_in[3];
  const float* bc2 = (const float*)d_in[4];
  const float* Wo1 = (const float*)d_in[5];
  const float* bo1 = (const float*)d_in[6];
  const float* Wo2 = (const float*)d_in[7];
  const float* bo2 = (const float*)d_in[8];
  const float* Wr1 = (const float*)d_in[9];
  const float* br1 = (const float*)d_in[10];
  const float* Wr2 = (const float*)d_in[11];
  const float* br2 = (const float*)d_in[12];
  const float* Wa  = (const float*)d_in[13];
  const float* ba  = (const float*)d_in[14];
  const float* We1 = (const float*)d_in[15];
  const float* be1 = (const float*)d_in[16];
  const float* We2 = (const float*)d_in[17];
  const float* be2 = (const float*)d_in[18];
  const float* We3 = (const float*)d_in[19];
  const float* be3 = (const float*)d_in[20];
  float* out = (float*)d_out;  // fp32 output

  char* p = (char*)d_ws;
  auto carve = [&](size_t bytes) {
    char* r = p;
    p += (bytes + 255) & ~(size_t)255;
    return r;
  };
  u16* xh   = (u16*)carve((size_t)B_ROWS * DIM * 2);       // 32MB
  u16* xl   = (u16*)carve((size_t)B_ROWS * DIM * 2);       // 32MB
  u16* Tc1h = (u16*)carve((size_t)DIM * DIM * 2);          // 2MB
  u16* Tc1l = (u16*)carve((size_t)DIM * DIM * 2);          // 2MB
  u16* Tall = (u16*)carve((size_t)NFUSE * DIM * 2);        // 5MB: To1|Tr1|Ta
  u16* Te1  = (u16*)carve((size_t)NEXP * DIM * DIM * 2);   // 14MB
  u16* Te2  = (u16*)carve((size_t)NEXP * DIM * DIM * 2);   // 14MB
  u16* DF   = (u16*)carve((size_t)B_ROWS * DIM * 2);       // 32MB (adapter out)
  float* zacc = (float*)carve((size_t)17 * B_ROWS * 4);    // 1.1MB contiguous
  int* size_idx = (int*)carve((size_t)B_ROWS * 4);
  int* perm   = (int*)carve((size_t)B_ROWS * 4);
  int* gcnt   = (int*)carve(256);
  int* cursor = (int*)carve(256);
  // acc sub-slices (contiguous inside zacc):
  float* ordacc = zacc;                 // [16384][6]
  float* resacc = zacc + 6 * B_ROWS;    // [16384]
  float* clsacc = zacc + 7 * B_ROWS;    // [16384][7]
  float* dlacc  = zacc + 14 * B_ROWS;   // [16384][3]
  // aliases over dead intervals (stream-ordered):
  u16* H1p = xl;  // xl dead after mega_gemm (cls pass 3)
  u16* To1 = Tall;                               // fused B rows [0,512)
  u16* Tr1 = Tall + (size_t)ORDH * DIM;          // rows [512,1536)
  u16* Ta  = Tall + (size_t)(ORDH + DIM) * DIM;  // rows [1536,2560)

  dim3 blk(256);
  convert_x_kernel<<<dim3(B_ROWS * DIM / 4 / 256), blk, 0, stream>>>(
      (const float4*)x, (ushort4*)xh, (ushort4*)xl, gcnt, cursor, zacc);
  transpose_all_kernel<<<dim3(17920), blk, 0, stream>>>(
      Wc1, Tc1h, Tc1l, Wo1, To1, Wr1, Tr1, Wa, Ta, We1, Te1, We2, Te2);

  // one dispatch: ord+res+adapter (1-pass) and cls (3-pass hi/lo), heads fused
  mega_gemm_kernel<<<dim3(NMEGA / 128, B_ROWS / 128), blk, 0, stream>>>(
      xh, xl, Tall, Tc1h, Tc1l, bo1, br1, ba, bc1, Wo2, Wr2, Wc2,
      ordacc, resacc, clsacc, DF);
  finalize_cls_kernel<<<dim3(B_ROWS / 256), blk, 0, stream>>>(
      ordacc, bo2, resacc, br2, clsacc, bc2, out, size_idx, gcnt);
  scatter_kernel<<<dim3(B_ROWS / 256), blk, 0, stream>>>(size_idx, gcnt, cursor, perm);

  // expert1 gathers A rows through perm; expert2 fuses head_dl (no H2 buffer)
  mgemm_expert1_kernel<<<dim3(DIM / 128, B_ROWS / 128, NEXP), blk, 0, stream>>>(
      DF, Te1, be1, gcnt, perm, H1p);
  mgemm_expert2_kernel<<<dim3(DIM / 128, B_ROWS / 128, NEXP), blk, 0, stream>>>(
      H1p, Te2, be2, gcnt, We3, dlacc);
  finalize_dl_kernel<<<dim3(B_ROWS / 256), blk, 0, stream>>>(
      dlacc, be3, gcnt, perm, out);
}

// Round 6
// 589.369 us; speedup vs baseline: 1.3722x; 1.3722x over previous
//
#include <hip/hip_runtime.h>
#include <cstdint>
#include <cstddef>

typedef unsigned short u16;
typedef u16 u16x8 __attribute__((ext_vector_type(8)));
typedef __bf16 bf16x8 __attribute__((ext_vector_type(8)));
typedef float f32x4 __attribute__((ext_vector_type(4)));

#define B_ROWS 16384
#define DIM 1024
#define ORDH 512
#define NEXP 7
#define NFUSE 2560   // 512 (ord) + 1024 (res) + 1024 (adapter)
#define NMEGA 3584   // NFUSE + 1024 (cls)

__device__ __forceinline__ u16 f2bf(float f) {
  unsigned u = __builtin_bit_cast(unsigned, f);
  u += 0x7FFFu + ((u >> 16) & 1u);  // RNE
  return (u16)(u >> 16);
}
__device__ __forceinline__ float bf2f(u16 h) {
  return __builtin_bit_cast(float, ((unsigned)h) << 16);
}

// async global->LDS, 16B per lane (global_load_lds_dwordx4)
typedef __attribute__((address_space(1))) const void gas_void;
typedef __attribute__((address_space(3))) void las_void;
__device__ __forceinline__ void gload16(const void* g, void* l) {
  __builtin_amdgcn_global_load_lds((gas_void*)g, (las_void*)l, 16, 0, 0);
}

// x fp32 -> bf16 hi + lo; zeroes gcnt/cursor.
__global__ __launch_bounds__(256) void convert_x_kernel(
    const float4* __restrict__ x, ushort4* __restrict__ xh,
    ushort4* __restrict__ xl, int* __restrict__ gcnt, int* __restrict__ cursor) {
  if (blockIdx.x == 0 && threadIdx.x < 2 * NEXP) {
    if (threadIdx.x < NEXP) gcnt[threadIdx.x] = 0;
    else cursor[threadIdx.x - NEXP] = 0;
  }
  const int i = blockIdx.x * 256 + threadIdx.x;
  float4 v = x[i];
  ushort4 h, l;
  h.x = f2bf(v.x); l.x = f2bf(v.x - bf2f(h.x));
  h.y = f2bf(v.y); l.y = f2bf(v.y - bf2f(h.y));
  h.z = f2bf(v.z); l.z = f2bf(v.z - bf2f(h.z));
  h.w = f2bf(v.w); l.w = f2bf(v.w - bf2f(h.w));
  xh[i] = h; xl[i] = l;
}

// ALL weight transposes in one launch. W [K][N] f32 -> WT [N][K] bf16.
__global__ __launch_bounds__(256) void transpose_all_kernel(
    const float* __restrict__ Wc1, u16* __restrict__ Tc1h, u16* __restrict__ Tc1l,
    const float* __restrict__ Wo1, u16* __restrict__ To1,
    const float* __restrict__ Wr1, u16* __restrict__ Tr1,
    const float* __restrict__ Wa,  u16* __restrict__ Ta,
    const float* __restrict__ We1, u16* __restrict__ Te1,
    const float* __restrict__ We2, u16* __restrict__ Te2) {
  __shared__ float tile[32][33];
  int bid = blockIdx.x;
  const float* W; u16* H; u16* L = nullptr;
  int N = 1024, bx, by;
  size_t zoff = 0;
  if (bid < 1024)      { W = Wc1; H = Tc1h; L = Tc1l; bx = bid & 31; by = bid >> 5; }
  else if (bid < 1536) { bid -= 1024; W = Wo1; H = To1; N = 512; bx = bid & 15; by = bid >> 4; }
  else if (bid < 2560) { bid -= 1536; W = Wr1; H = Tr1; bx = bid & 31; by = bid >> 5; }
  else if (bid < 3584) { bid -= 2560; W = Wa; H = Ta; bx = bid & 31; by = bid >> 5; }
  else if (bid < 10752){ bid -= 3584; W = We1; H = Te1;
                         zoff = (size_t)(bid >> 10) * DIM * DIM; bid &= 1023;
                         bx = bid & 31; by = bid >> 5; }
  else                 { bid -= 10752; W = We2; H = Te2;
                         zoff = (size_t)(bid >> 10) * DIM * DIM; bid &= 1023;
                         bx = bid & 31; by = bid >> 5; }
  const int K = 1024;
  const int bk = by * 32, bn = bx * 32;
  const int tx = threadIdx.x & 31, ty = threadIdx.x >> 5;  // 32 x 8
#pragma unroll
  for (int r = 0; r < 32; r += 8)
    tile[ty + r][tx] = W[zoff + (size_t)(bk + ty + r) * N + (bn + tx)];
  __syncthreads();
#pragma unroll
  for (int r = 0; r < 32; r += 8) {
    const float v = tile[tx][ty + r];
    const size_t o = zoff + (size_t)(bn + ty + r) * K + (bk + tx);
    const u16 h = f2bf(v);
    H[o] = h;
    if (L) L[o] = f2bf(v - bf2f(h));
  }
}

// ---------------------------------------------------------------------------
// GEMM core (R2 structure, proven ~900 TF @K=1024): 128x128x64 tile, 4 waves,
// 4x4 mfma 16x16x32. global_load_lds width-16 into LINEAR LDS; T2 both-sides
// swizzle; double-buffer 2x32KB; counted s_waitcnt vmcnt(8), never drained.
// B pointer pre-offset by its row panel.
// ---------------------------------------------------------------------------
__device__ __forceinline__ void gemm_loop(
    const u16* __restrict__ aP0, const u16* __restrict__ bP0,
    const u16* __restrict__ aP1, const u16* __restrict__ bP1,
    const u16* __restrict__ aP2, const u16* __restrict__ bP2,
    int npass, int K, int m0, u16* SM, int tid, f32x4 (&acc)[4][4]) {
  const int lane = tid & 63;
  const int w = tid >> 6;
  const int wm = w >> 1, wn = w & 1;
  const int sRow = tid >> 3, sSlot = tid & 7;  // 32 rows x 8 chunks(16B)
  const int ldsOff = sRow * 64 + sSlot * 8;
  const size_t aOff = (size_t)(m0 + sRow) * K + ((sSlot ^ (sRow & 7)) * 8);
  const size_t bOff = (size_t)sRow * K + ((sSlot ^ (sRow & 7)) * 8);
  const u16* aCur = aP0 + aOff;
  const u16* bCur = bP0 + bOff;
  int sp = 0, sk = 0;  // next tile to stage
  auto stageNext = [&](int b) {
    u16* d = SM + b * 16384 + ldsOff;
    const u16* as = aCur + sk;
    const u16* bs = bCur + sk;
#pragma unroll
    for (int r = 0; r < 4; ++r) {
      gload16(as + (size_t)(r * 32) * K, d + r * 32 * 64);
      gload16(bs + (size_t)(r * 32) * K, d + 8192 + r * 32 * 64);
    }
    sk += 64;
    if (sk == K) {
      sk = 0; ++sp;
      if (sp == 1) { aCur = aP1 + aOff; bCur = bP1 + bOff; }
      else         { aCur = aP2 + aOff; bCur = bP2 + bOff; }
    }
  };

  const int ntiles = npass * (K >> 6);
  stageNext(0);
  int cur = 0;
  for (int ti = 0; ti < ntiles; ++ti) {
    if (ti + 1 < ntiles) {
      stageNext(cur ^ 1);
      asm volatile("s_waitcnt vmcnt(8)\n\ts_barrier" ::: "memory");
    } else {
      asm volatile("s_waitcnt vmcnt(0)\n\ts_barrier" ::: "memory");
    }
    const u16* As = SM + cur * 16384;
    const u16* Bs = As + 8192;
#pragma unroll
    for (int s = 0; s < 2; ++s) {
      const int cAx = s * 4 + (lane >> 4);
      const int colO = (cAx ^ (lane & 7)) * 8;  // T2 swizzled read chunk
      bf16x8 af[4], bfr[4];
#pragma unroll
      for (int t = 0; t < 4; ++t) {
        const int rowA = wm * 64 + t * 16 + (lane & 15);
        af[t] = __builtin_bit_cast(bf16x8, *(const u16x8*)&As[rowA * 64 + colO]);
        const int rowB = wn * 64 + t * 16 + (lane & 15);
        bfr[t] = __builtin_bit_cast(bf16x8, *(const u16x8*)&Bs[rowB * 64 + colO]);
      }
#pragma unroll
      for (int mt = 0; mt < 4; ++mt)
#pragma unroll
        for (int nt = 0; nt < 4; ++nt)
          acc[mt][nt] = __builtin_amdgcn_mfma_f32_16x16x32_bf16(
              af[mt], bfr[nt], acc[mt][nt], 0, 0, 0);
    }
    asm volatile("s_barrier" ::: "memory");
    cur ^= 1;
  }
}

// ---------------------------------------------------------------------------
// mega GEMM: 28 col-tiles x 128 row-tiles, one dispatch. Head partials are
// written as PRIVATE depth-slices (no atomics — R5 post-mortem: 4M device-
// scope atomics serialized cross-XCD, +200us). Writer of slice d = tile*2+wn
// is unique per row. Layout part[(d*W + n)*B + row] -> finalize reads coalesce.
//   cols [0,512):      ord hidden  -> ordpart, 8 slices x 6
//   cols [512,1536):   res hidden  -> respart, 16 slices x 1
//   cols [1536,2560):  adapter     -> DF bf16 store
//   cols [2560,3584):  cls 3-pass hi/lo -> clspart, 16 slices x 7
// Heavy-first column remap: cls tiles issue first per XCD (shrinks tail).
// ---------------------------------------------------------------------------
__global__ __launch_bounds__(256, 2) void mega_gemm_kernel(
    const u16* __restrict__ xh, const u16* __restrict__ xl,
    const u16* __restrict__ Tall, const u16* __restrict__ Tc1h,
    const u16* __restrict__ Tc1l,
    const float* __restrict__ bo1, const float* __restrict__ br1,
    const float* __restrict__ ba, const float* __restrict__ bc1,
    const float* __restrict__ Wo2, const float* __restrict__ Wr2,
    const float* __restrict__ Wc2,
    float* __restrict__ ordpart, float* __restrict__ respart,
    float* __restrict__ clspart, u16* __restrict__ DF) {
  __shared__ __attribute__((aligned(16))) u16 SM[4 * 128 * 64];
  const int tid = threadIdx.x;
  const int lane = tid & 63;
  const int w = tid >> 6;
  const int wm = w >> 1, wn = w & 1;
  // XCD-aware bijective swizzle (nwg = 3584, % 8 == 0)
  const unsigned nwg = 3584u;
  const unsigned wgid = blockIdx.y * gridDim.x + blockIdx.x;
  const unsigned swz = (wgid & 7u) * (nwg >> 3) + (wgid >> 3);
  const int m0 = (int)(swz / 28u) * 128;
  const int pp = (int)(swz % 28u);
  const int ct = (pp < 8) ? (20 + pp) : (pp - 8);  // heavy (cls) first
  const int n0 = ct * 128;

  f32x4 acc[4][4] = {};
  if (n0 < NFUSE) {
    const u16* b = Tall + (size_t)n0 * DIM;
    gemm_loop(xh, b, xh, b, xh, b, 1, DIM, m0, SM, tid, acc);
  } else {
    const u16* bh = Tc1h + (size_t)(n0 - NFUSE) * DIM;
    const u16* bl = Tc1l + (size_t)(n0 - NFUSE) * DIM;
    gemm_loop(xh, bh, xh, bl, xl, bh, 3, DIM, m0, SM, tid, acc);
  }

  const int q = lane >> 4, cl = lane & 15;
  if (n0 < ORDH) {
    const int d = (n0 >> 7) * 2 + wn;  // 0..7
#pragma unroll
    for (int mt = 0; mt < 4; ++mt)
#pragma unroll
      for (int i = 0; i < 4; ++i) {
        const int row = m0 + wm * 64 + mt * 16 + q * 4 + i;
        float s[6] = {0, 0, 0, 0, 0, 0};
#pragma unroll
        for (int nt = 0; nt < 4; ++nt) {
          const int col = n0 + wn * 64 + nt * 16 + cl;
          float v = acc[mt][nt][i] + bo1[col];
          v = v > 0.f ? v : 0.f;
          const float* wr = Wo2 + col * 6;
#pragma unroll
          for (int n = 0; n < 6; ++n) s[n] += v * wr[n];
        }
#pragma unroll
        for (int n = 0; n < 6; ++n) {
          s[n] += __shfl_xor(s[n], 1);
          s[n] += __shfl_xor(s[n], 2);
          s[n] += __shfl_xor(s[n], 4);
          s[n] += __shfl_xor(s[n], 8);
        }
        if (cl == 0)
#pragma unroll
          for (int n = 0; n < 6; ++n)
            ordpart[(size_t)(d * 6 + n) * B_ROWS + row] = s[n];
      }
  } else if (n0 < ORDH + DIM) {
    const int d = ((n0 - ORDH) >> 7) * 2 + wn;  // 0..15
#pragma unroll
    for (int mt = 0; mt < 4; ++mt)
#pragma unroll
      for (int i = 0; i < 4; ++i) {
        const int row = m0 + wm * 64 + mt * 16 + q * 4 + i;
        float s = 0.f;
#pragma unroll
        for (int nt = 0; nt < 4; ++nt) {
          const int hc = n0 - ORDH + wn * 64 + nt * 16 + cl;
          float v = acc[mt][nt][i] + br1[hc];
          v = v > 0.f ? v : 0.f;
          s += v * Wr2[hc];
        }
        s += __shfl_xor(s, 1);
        s += __shfl_xor(s, 2);
        s += __shfl_xor(s, 4);
        s += __shfl_xor(s, 8);
        if (cl == 0) respart[(size_t)d * B_ROWS + row] = s;
      }
  } else if (n0 < NFUSE) {
    // adapter: materialize DF (experts consume it)
#pragma unroll
    for (int nt = 0; nt < 4; ++nt) {
      const int col = n0 - (ORDH + DIM) + wn * 64 + nt * 16 + cl;
      const float bv = ba[col];
#pragma unroll
      for (int mt = 0; mt < 4; ++mt)
#pragma unroll
        for (int i = 0; i < 4; ++i) {
          const int row = m0 + wm * 64 + mt * 16 + q * 4 + i;
          float v = acc[mt][nt][i] + bv;
          v = v > 0.f ? v : 0.f;
          DF[(size_t)row * DIM + col] = f2bf(v);
        }
    }
  } else {
    const int d = ((n0 - NFUSE) >> 7) * 2 + wn;  // 0..15
#pragma unroll
    for (int mt = 0; mt < 4; ++mt)
#pragma unroll
      for (int i = 0; i < 4; ++i) {
        const int row = m0 + wm * 64 + mt * 16 + q * 4 + i;
        float s[7] = {0, 0, 0, 0, 0, 0, 0};
#pragma unroll
        for (int nt = 0; nt < 4; ++nt) {
          const int hc = n0 - NFUSE + wn * 64 + nt * 16 + cl;
          float v = acc[mt][nt][i] + bc1[hc];
          v = v > 0.f ? v : 0.f;
          const float* wr = Wc2 + hc * 7;
#pragma unroll
          for (int n = 0; n < 7; ++n) s[n] += v * wr[n];
        }
#pragma unroll
        for (int n = 0; n < 7; ++n) {
          s[n] += __shfl_xor(s[n], 1);
          s[n] += __shfl_xor(s[n], 2);
          s[n] += __shfl_xor(s[n], 4);
          s[n] += __shfl_xor(s[n], 8);
        }
        if (cl == 0)
#pragma unroll
          for (int n = 0; n < 7; ++n)
            clspart[(size_t)(d * 7 + n) * B_ROWS + row] = s[n];
      }
  }
}

// expert1: rows [base+t0, base+cnt[e]), A gathered through perm; writes H1p.
__global__ __launch_bounds__(256, 2) void mgemm_expert1_kernel(
    const u16* __restrict__ Abuf, const u16* __restrict__ Wall,
    const float* __restrict__ biasAll, const int* __restrict__ cnt,
    const int* __restrict__ perm, u16* __restrict__ outH) {
  __shared__ __attribute__((aligned(16))) u16 SM[4 * 128 * 64];
  const int e = blockIdx.z;
  const int myCnt = cnt[e];
  const int t0 = blockIdx.y * 128;
  if (t0 >= myCnt) return;
  int base = 0;
  for (int t = 0; t < NEXP; ++t) base += (t < e) ? cnt[t] : 0;
  const int m0 = base + t0;
  const int mEnd = base + myCnt;
  const u16* Bp = Wall + (size_t)e * DIM * DIM;
  const float* bias = biasAll + (size_t)e * DIM;

  const int tid = threadIdx.x;
  const int lane = tid & 63;
  const int w = tid >> 6;
  const int wm = w >> 1, wn = w & 1;
  const int n0 = blockIdx.x * 128;
  const int sRow = tid >> 3, sSlot = tid & 7;
  const int ldsOff = sRow * 64 + sSlot * 8;
  const int swzC = (sSlot ^ (sRow & 7)) * 8;

  const u16* aSrc[4];
#pragma unroll
  for (int r = 0; r < 4; ++r) {
    int ar = m0 + r * 32 + sRow;
    if (ar > B_ROWS - 1) ar = B_ROWS - 1;
    aSrc[r] = Abuf + (size_t)perm[ar] * DIM + swzC;
  }
  const u16* bSrc = Bp + (size_t)(n0 + sRow) * DIM + swzC;

  int sk = 0;
  auto stageNext = [&](int b) {
    u16* d = SM + b * 16384 + ldsOff;
#pragma unroll
    for (int r = 0; r < 4; ++r)
      gload16(aSrc[r] + sk, d + r * 32 * 64);
#pragma unroll
    for (int r = 0; r < 4; ++r)
      gload16(bSrc + (size_t)(r * 32) * DIM + sk, d + 8192 + r * 32 * 64);
    sk += 64;
  };

  f32x4 acc[4][4] = {};
  const int ntiles = DIM >> 6;
  stageNext(0);
  int cur = 0;
  for (int ti = 0; ti < ntiles; ++ti) {
    if (ti + 1 < ntiles) {
      stageNext(cur ^ 1);
      asm volatile("s_waitcnt vmcnt(8)\n\ts_barrier" ::: "memory");
    } else {
      asm volatile("s_waitcnt vmcnt(0)\n\ts_barrier" ::: "memory");
    }
    const u16* As = SM + cur * 16384;
    const u16* Bs = As + 8192;
#pragma unroll
    for (int s = 0; s < 2; ++s) {
      const int cAx = s * 4 + (lane >> 4);
      const int colO = (cAx ^ (lane & 7)) * 8;
      bf16x8 af[4], bfr[4];
#pragma unroll
      for (int t = 0; t < 4; ++t) {
        const int rowA = wm * 64 + t * 16 + (lane & 15);
        af[t] = __builtin_bit_cast(bf16x8, *(const u16x8*)&As[rowA * 64 + colO]);
        const int rowB = wn * 64 + t * 16 + (lane & 15);
        bfr[t] = __builtin_bit_cast(bf16x8, *(const u16x8*)&Bs[rowB * 64 + colO]);
      }
#pragma unroll
      for (int mt = 0; mt < 4; ++mt)
#pragma unroll
        for (int nt = 0; nt < 4; ++nt)
          acc[mt][nt] = __builtin_amdgcn_mfma_f32_16x16x32_bf16(
              af[mt], bfr[nt], acc[mt][nt], 0, 0, 0);
    }
    asm volatile("s_barrier" ::: "memory");
    cur ^= 1;
  }

  const int q = lane >> 4, cl = lane & 15;
#pragma unroll
  for (int nt = 0; nt < 4; ++nt) {
    const int col = n0 + wn * 64 + nt * 16 + cl;
    const float bv = bias[col];
#pragma unroll
    for (int mt = 0; mt < 4; ++mt) {
#pragma unroll
      for (int i = 0; i < 4; ++i) {
        const int row = m0 + wm * 64 + mt * 16 + q * 4 + i;
        if (row < mEnd) {
          float v = acc[mt][nt][i] + bv;
          v = v > 0.f ? v : 0.f;
          outH[(size_t)row * DIM + col] = f2bf(v);
        }
      }
    }
  }
}

// expert2: GEMM + fused head_dl via partial-store slices (d = ntile*2+wn).
// H2 never materialized.
__global__ __launch_bounds__(256, 2) void mgemm_expert2_kernel(
    const u16* __restrict__ Abuf, const u16* __restrict__ Wall,
    const float* __restrict__ biasAll, const int* __restrict__ cnt,
    const float* __restrict__ We3, float* __restrict__ dlpart) {
  __shared__ __attribute__((aligned(16))) u16 SM[4 * 128 * 64];
  const int e = blockIdx.z;
  const int myCnt = cnt[e];
  const int t0 = blockIdx.y * 128;
  if (t0 >= myCnt) return;
  int base = 0;
  for (int t = 0; t < NEXP; ++t) base += (t < e) ? cnt[t] : 0;
  const int m0 = base + t0;
  const int mEnd = base + myCnt;
  const u16* Bp = Wall + (size_t)e * DIM * DIM;
  const float* bias = biasAll + (size_t)e * DIM;
  const float* W3 = We3 + (size_t)e * DIM * 3;

  const int tid = threadIdx.x;
  const int lane = tid & 63;
  const int w = tid >> 6;
  const int wm = w >> 1, wn = w & 1;
  const int n0 = blockIdx.x * 128;
  const int sRow = tid >> 3, sSlot = tid & 7;
  const int ldsOff = sRow * 64 + sSlot * 8;
  const int swzC = (sSlot ^ (sRow & 7)) * 8;

  const u16* aSrc[4];
#pragma unroll
  for (int r = 0; r < 4; ++r) {
    int ar = m0 + r * 32 + sRow;
    if (ar > B_ROWS - 1) ar = B_ROWS - 1;
    aSrc[r] = Abuf + (size_t)ar * DIM + swzC;
  }
  const u16* bSrc = Bp + (size_t)(n0 + sRow) * DIM + swzC;

  int sk = 0;
  auto stageNext = [&](int b) {
    u16* d = SM + b * 16384 + ldsOff;
#pragma unroll
    for (int r = 0; r < 4; ++r)
      gload16(aSrc[r] + sk, d + r * 32 * 64);
#pragma unroll
    for (int r = 0; r < 4; ++r)
      gload16(bSrc + (size_t)(r * 32) * DIM + sk, d + 8192 + r * 32 * 64);
    sk += 64;
  };

  f32x4 acc[4][4] = {};
  const int ntiles = DIM >> 6;
  stageNext(0);
  int cur = 0;
  for (int ti = 0; ti < ntiles; ++ti) {
    if (ti + 1 < ntiles) {
      stageNext(cur ^ 1);
      asm volatile("s_waitcnt vmcnt(8)\n\ts_barrier" ::: "memory");
    } else {
      asm volatile("s_waitcnt vmcnt(0)\n\ts_barrier" ::: "memory");
    }
    const u16* As = SM + cur * 16384;
    const u16* Bs = As + 8192;
#pragma unroll
    for (int s = 0; s < 2; ++s) {
      const int cAx = s * 4 + (lane >> 4);
      const int colO = (cAx ^ (lane & 7)) * 8;
      bf16x8 af[4], bfr[4];
#pragma unroll
      for (int t = 0; t < 4; ++t) {
        const int rowA = wm * 64 + t * 16 + (lane & 15);
        af[t] = __builtin_bit_cast(bf16x8, *(const u16x8*)&As[rowA * 64 + colO]);
        const int rowB = wn * 64 + t * 16 + (lane & 15);
        bfr[t] = __builtin_bit_cast(bf16x8, *(const u16x8*)&Bs[rowB * 64 + colO]);
      }
#pragma unroll
      for (int mt = 0; mt < 4; ++mt)
#pragma unroll
        for (int nt = 0; nt < 4; ++nt)
          acc[mt][nt] = __builtin_amdgcn_mfma_f32_16x16x32_bf16(
              af[mt], bfr[nt], acc[mt][nt], 0, 0, 0);
    }
    asm volatile("s_barrier" ::: "memory");
    cur ^= 1;
  }

  const int q = lane >> 4, cl = lane & 15;
  const int d = (n0 >> 7) * 2 + wn;  // 0..15
#pragma unroll
  for (int mt = 0; mt < 4; ++mt)
#pragma unroll
    for (int i = 0; i < 4; ++i) {
      const int row = m0 + wm * 64 + mt * 16 + q * 4 + i;
      float s0 = 0.f, s1 = 0.f, s2 = 0.f;
#pragma unroll
      for (int nt = 0; nt < 4; ++nt) {
        const int col = n0 + wn * 64 + nt * 16 + cl;
        float v = acc[mt][nt][i] + bias[col];
        v = v > 0.f ? v : 0.f;
        const float* wr = W3 + col * 3;
        s0 += v * wr[0]; s1 += v * wr[1]; s2 += v * wr[2];
      }
      s0 += __shfl_xor(s0, 1); s0 += __shfl_xor(s0, 2);
      s0 += __shfl_xor(s0, 4); s0 += __shfl_xor(s0, 8);
      s1 += __shfl_xor(s1, 1); s1 += __shfl_xor(s1, 2);
      s1 += __shfl_xor(s1, 4); s1 += __shfl_xor(s1, 8);
      s2 += __shfl_xor(s2, 1); s2 += __shfl_xor(s2, 2);
      s2 += __shfl_xor(s2, 4); s2 += __shfl_xor(s2, 8);
      if (cl == 0 && row < mEnd) {
        dlpart[(size_t)(d * 3 + 0) * B_ROWS + row] = s0;
        dlpart[(size_t)(d * 3 + 1) * B_ROWS + row] = s1;
        dlpart[(size_t)(d * 3 + 2) * B_ROWS + row] = s2;
      }
    }
}

// ---------------------------------------------------------------------------
// finalize: one thread per row; sums depth slices (coalesced reads).
// ---------------------------------------------------------------------------
__global__ __launch_bounds__(256) void finalize_cls_kernel(
    const float* __restrict__ ordpart, const float* __restrict__ bo2,
    const float* __restrict__ respart, const float* __restrict__ br2,
    const float* __restrict__ clspart, const float* __restrict__ bc2,
    float* __restrict__ out, int* __restrict__ size_idx, int* __restrict__ gcnt) {
  __shared__ int lcnt[NEXP];
  const int tid = threadIdx.x;
  if (tid < NEXP) lcnt[tid] = 0;
  __syncthreads();
  const int r = blockIdx.x * 256 + tid;
  float ov[6] = {0, 0, 0, 0, 0, 0};
#pragma unroll
  for (int d = 0; d < 8; ++d)
#pragma unroll
    for (int n = 0; n < 6; ++n) ov[n] += ordpart[(size_t)(d * 6 + n) * B_ROWS + r];
  float rs = 0.f;
#pragma unroll
  for (int d = 0; d < 16; ++d) rs += respart[(size_t)d * B_ROWS + r];
  float lg[7] = {0, 0, 0, 0, 0, 0, 0};
#pragma unroll
  for (int d = 0; d < 16; ++d)
#pragma unroll
    for (int n = 0; n < 7; ++n) lg[n] += clspart[(size_t)(d * 7 + n) * B_ROWS + r];

  float* orow = out + (size_t)r * 24;
#pragma unroll
  for (int n = 0; n < 6; ++n) orow[7 + n] = ov[n] + bo2[n];
  const float resv = 0.35f * tanhf(rs + br2[0]);
  float pb[7];
  float m = -1e30f;
  int ai = 0;
#pragma unroll
  for (int n = 0; n < 7; ++n) {
    lg[n] += bc2[n];
    if (lg[n] > m) { m = lg[n]; ai = n; }  // first max == np.argmax
  }
  float es = 0.f;
#pragma unroll
  for (int n = 0; n < 7; ++n) { pb[n] = expf(lg[n] - m); es += pb[n]; }
  const float inv = 1.f / es;
  float expect = 0.f;
#pragma unroll
  for (int n = 0; n < 7; ++n) { pb[n] *= inv; expect += pb[n] * (n * (1.f / 6.f)); }
  float reg = expect + resv;
  reg = fminf(fmaxf(reg, 0.f), 1.f);
#pragma unroll
  for (int n = 0; n < 7; ++n) orow[n] = lg[n];
  orow[13] = reg;
#pragma unroll
  for (int n = 0; n < 7; ++n) orow[14 + n] = pb[n];
  size_idx[r] = ai;
  atomicAdd(&lcnt[ai], 1);
  __syncthreads();
  if (tid < NEXP && lcnt[tid] > 0) atomicAdd(&gcnt[tid], lcnt[tid]);
}

// scatter: off computed locally from final gcnt; cursor pre-zeroed.
__global__ __launch_bounds__(256) void scatter_kernel(
    const int* __restrict__ size_idx, const int* __restrict__ gcnt,
    int* __restrict__ cursor, int* __restrict__ perm) {
  __shared__ int lcnt[NEXP];
  __shared__ int lbase[NEXP];
  const int tid = threadIdx.x;
  if (tid < NEXP) lcnt[tid] = 0;
  __syncthreads();
  const int r = blockIdx.x * 256 + tid;
  const int e = size_idx[r];
  const int lp = atomicAdd(&lcnt[e], 1);
  __syncthreads();
  if (tid < NEXP && lcnt[tid] > 0) {
    int off = 0;
    for (int t = 0; t < tid; ++t) off += gcnt[t];
    lbase[tid] = off + atomicAdd(&cursor[tid], lcnt[tid]);
  }
  __syncthreads();
  perm[lbase[e] + lp] = r;
}

__global__ __launch_bounds__(256) void finalize_dl_kernel(
    const float* __restrict__ dlpart, const float* __restrict__ be3,
    const int* __restrict__ gcnt, const int* __restrict__ perm,
    float* __restrict__ out) {
  const int i = blockIdx.x * 256 + threadIdx.x;
  int e = 0, a = 0;
#pragma unroll
  for (int t = 0; t < NEXP - 1; ++t) {
    a += gcnt[t];
    if (i >= a) e = t + 1;
  }
  float s[3] = {0, 0, 0};
#pragma unroll
  for (int d = 0; d < 16; ++d)
#pragma unroll
    for (int c = 0; c < 3; ++c) s[c] += dlpart[(size_t)(d * 3 + c) * B_ROWS + i];
  const int r = perm[i];
  float* orow = out + (size_t)r * 24;
#pragma unroll
  for (int c = 0; c < 3; ++c) orow[21 + c] = s[c] + be3[e * 3 + c];
}

// ---------------------------------------------------------------------------
extern "C" void kernel_launch(void* const* d_in, const int* in_sizes, int n_in,
                              void* d_out, int out_size, void* d_ws, size_t ws_size,
                              hipStream_t stream) {
  (void)in_sizes; (void)n_in; (void)out_size; (void)ws_size;
  const float* x   = (const float*)d_in[0];
  const float* Wc1 = (const float*)d_in[1];
  const float* bc1 = (const float*)d_in[2];
  const float* Wc2 = (const float*)d_in[3];
  const float* bc2 = (const float*)d_in[4];
  const float* Wo1 = (const float*)d_in[5];
  const float* bo1 = (const float*)d_in[6];
  const float* Wo2 = (const float*)d_in[7];
  const float* bo2 = (const float*)d_in[8];
  const float* Wr1 = (const float*)d_in[9];
  const float* br1 = (const float*)d_in[10];
  const float* Wr2 = (const float*)d_in[11];
  const float* br2 = (const float*)d_in[12];
  const float* Wa  = (const float*)d_in[13];
  const float* ba  = (const float*)d_in[14];
  const float* We1 = (const float*)d_in[15];
  const float* be1 = (const float*)d_in[16];
  const float* We2 = (const float*)d_in[17];
  const float* be2 = (const float*)d_in[18];
  const float* We3 = (const float*)d_in[19];
  const float* be3 = (const float*)d_in[20];
  float* out = (float*)d_out;  // fp32 output

  char* p = (char*)d_ws;
  auto carve = [&](size_t bytes) {
    char* r = p;
    p += (bytes + 255) & ~(size_t)255;
    return r;
  };
  u16* xh   = (u16*)carve((size_t)B_ROWS * DIM * 2);       // 32MB
  u16* xl   = (u16*)carve((size_t)B_ROWS * DIM * 2);       // 32MB
  u16* Tc1h = (u16*)carve((size_t)DIM * DIM * 2);          // 2MB
  u16* Tc1l = (u16*)carve((size_t)DIM * DIM * 2);          // 2MB
  u16* Tall = (u16*)carve((size_t)NFUSE * DIM * 2);        // 5MB: To1|Tr1|Ta
  u16* Te1  = (u16*)carve((size_t)NEXP * DIM * DIM * 2);   // 14MB
  u16* Te2  = (u16*)carve((size_t)NEXP * DIM * DIM * 2);   // 14MB
  u16* DF   = (u16*)carve((size_t)B_ROWS * DIM * 2);       // 32MB (adapter out)
  float* ordpart = (float*)carve((size_t)8 * 6 * B_ROWS * 4);   // 3MB
  float* respart = (float*)carve((size_t)16 * B_ROWS * 4);      // 1MB
  float* clspart = (float*)carve((size_t)16 * 7 * B_ROWS * 4);  // 7.3MB
  float* dlpart  = (float*)carve((size_t)16 * 3 * B_ROWS * 4);  // 3MB
  int* size_idx = (int*)carve((size_t)B_ROWS * 4);
  int* perm   = (int*)carve((size_t)B_ROWS * 4);
  int* gcnt   = (int*)carve(256);
  int* cursor = (int*)carve(256);
  // aliases over dead intervals (stream-ordered):
  u16* H1p = xl;  // xl dead after mega_gemm (cls pass 3)
  u16* To1 = Tall;                               // fused B rows [0,512)
  u16* Tr1 = Tall + (size_t)ORDH * DIM;          // rows [512,1536)
  u16* Ta  = Tall + (size_t)(ORDH + DIM) * DIM;  // rows [1536,2560)

  dim3 blk(256);
  convert_x_kernel<<<dim3(B_ROWS * DIM / 4 / 256), blk, 0, stream>>>(
      (const float4*)x, (ushort4*)xh, (ushort4*)xl, gcnt, cursor);
  transpose_all_kernel<<<dim3(17920), blk, 0, stream>>>(
      Wc1, Tc1h, Tc1l, Wo1, To1, Wr1, Tr1, Wa, Ta, We1, Te1, We2, Te2);

  // one dispatch: ord+res+adapter (1-pass) and cls (3-pass hi/lo), heads fused
  mega_gemm_kernel<<<dim3(NMEGA / 128, B_ROWS / 128), blk, 0, stream>>>(
      xh, xl, Tall, Tc1h, Tc1l, bo1, br1, ba, bc1, Wo2, Wr2, Wc2,
      ordpart, respart, clspart, DF);
  finalize_cls_kernel<<<dim3(B_ROWS / 256), blk, 0, stream>>>(
      ordpart, bo2, respart, br2, clspart, bc2, out, size_idx, gcnt);
  scatter_kernel<<<dim3(B_ROWS / 256), blk, 0, stream>>>(size_idx, gcnt, cursor, perm);

  // expert1 gathers A rows through perm; expert2 fuses head_dl (no H2 buffer)
  mgemm_expert1_kernel<<<dim3(DIM / 128, B_ROWS / 128, NEXP), blk, 0, stream>>>(
      DF, Te1, be1, gcnt, perm, H1p);
  mgemm_expert2_kernel<<<dim3(DIM / 128, B_ROWS / 128, NEXP), blk, 0, stream>>>(
      H1p, Te2, be2, gcnt, We3, dlpart);
  finalize_dl_kernel<<<dim3(B_ROWS / 256), blk, 0, stream>>>(
      dlpart, be3, gcnt, perm, out);
}

// Round 8
// 572.743 us; speedup vs baseline: 1.4121x; 1.0290x over previous
//
#include <hip/hip_runtime.h>
#include <cstdint>
#include <cstddef>

typedef unsigned short u16;
typedef u16 u16x8 __attribute__((ext_vector_type(8)));
typedef __bf16 bf16x8 __attribute__((ext_vector_type(8)));
typedef float f32x4 __attribute__((ext_vector_type(4)));

#define B_ROWS 16384
#define DIM 1024
#define ORDH 512
#define NEXP 7
#define NFUSE 2560   // 512 (ord) + 1024 (res) + 1024 (adapter)

__device__ __forceinline__ u16 f2bf(float f) {
  unsigned u = __builtin_bit_cast(unsigned, f);
  u += 0x7FFFu + ((u >> 16) & 1u);  // RNE
  return (u16)(u >> 16);
}
__device__ __forceinline__ float bf2f(u16 h) {
  return __builtin_bit_cast(float, ((unsigned)h) << 16);
}

// async global->LDS, 16B per lane (global_load_lds_dwordx4)
typedef __attribute__((address_space(1))) const void gas_void;
typedef __attribute__((address_space(3))) void las_void;
__device__ __forceinline__ void gload16(const void* g, void* l) {
  __builtin_amdgcn_global_load_lds((gas_void*)g, (las_void*)l, 16, 0, 0);
}

// x fp32 -> bf16 hi + lo; zeroes gcnt/cursor.
__global__ __launch_bounds__(256) void convert_x_kernel(
    const float4* __restrict__ x, ushort4* __restrict__ xh,
    ushort4* __restrict__ xl, int* __restrict__ gcnt, int* __restrict__ cursor) {
  if (blockIdx.x == 0 && threadIdx.x < 2 * NEXP) {
    if (threadIdx.x < NEXP) gcnt[threadIdx.x] = 0;
    else cursor[threadIdx.x - NEXP] = 0;
  }
  const int i = blockIdx.x * 256 + threadIdx.x;
  float4 v = x[i];
  ushort4 h, l;
  h.x = f2bf(v.x); l.x = f2bf(v.x - bf2f(h.x));
  h.y = f2bf(v.y); l.y = f2bf(v.y - bf2f(h.y));
  h.z = f2bf(v.z); l.z = f2bf(v.z - bf2f(h.z));
  h.w = f2bf(v.w); l.w = f2bf(v.w - bf2f(h.w));
  xh[i] = h; xl[i] = l;
}

// ALL weight transposes in one launch. W [K][N] f32 -> WT [N][K] bf16.
__global__ __launch_bounds__(256) void transpose_all_kernel(
    const float* __restrict__ Wc1, u16* __restrict__ Tc1h, u16* __restrict__ Tc1l,
    const float* __restrict__ Wo1, u16* __restrict__ To1,
    const float* __restrict__ Wr1, u16* __restrict__ Tr1,
    const float* __restrict__ Wa,  u16* __restrict__ Ta,
    const float* __restrict__ We1, u16* __restrict__ Te1,
    const float* __restrict__ We2, u16* __restrict__ Te2) {
  __shared__ float tile[32][33];
  int bid = blockIdx.x;
  const float* W; u16* H; u16* L = nullptr;
  int N = 1024, bx, by;
  size_t zoff = 0;
  if (bid < 1024)      { W = Wc1; H = Tc1h; L = Tc1l; bx = bid & 31; by = bid >> 5; }
  else if (bid < 1536) { bid -= 1024; W = Wo1; H = To1; N = 512; bx = bid & 15; by = bid >> 4; }
  else if (bid < 2560) { bid -= 1536; W = Wr1; H = Tr1; bx = bid & 31; by = bid >> 5; }
  else if (bid < 3584) { bid -= 2560; W = Wa; H = Ta; bx = bid & 31; by = bid >> 5; }
  else if (bid < 10752){ bid -= 3584; W = We1; H = Te1;
                         zoff = (size_t)(bid >> 10) * DIM * DIM; bid &= 1023;
                         bx = bid & 31; by = bid >> 5; }
  else                 { bid -= 10752; W = We2; H = Te2;
                         zoff = (size_t)(bid >> 10) * DIM * DIM; bid &= 1023;
                         bx = bid & 31; by = bid >> 5; }
  const int K = 1024;
  const int bk = by * 32, bn = bx * 32;
  const int tx = threadIdx.x & 31, ty = threadIdx.x >> 5;  // 32 x 8
#pragma unroll
  for (int r = 0; r < 32; r += 8)
    tile[ty + r][tx] = W[zoff + (size_t)(bk + ty + r) * N + (bn + tx)];
  __syncthreads();
#pragma unroll
  for (int r = 0; r < 32; r += 8) {
    const float v = tile[tx][ty + r];
    const size_t o = zoff + (size_t)(bn + ty + r) * K + (bk + tx);
    const u16 h = f2bf(v);
    H[o] = h;
    if (L) L[o] = f2bf(v - bf2f(h));
  }
}

// ---------------------------------------------------------------------------
// GEMM core (R2 structure, proven ~900 TF @K=1024): 128x128x64 tile, 4 waves,
// 4x4 mfma 16x16x32. global_load_lds width-16 into LINEAR LDS; T2 both-sides
// swizzle; double-buffer 2x32KB; counted s_waitcnt vmcnt(8), never drained.
// ---------------------------------------------------------------------------
__device__ __forceinline__ void gemm_loop(
    const u16* __restrict__ aP0, const u16* __restrict__ bP0,
    const u16* __restrict__ aP1, const u16* __restrict__ bP1,
    const u16* __restrict__ aP2, const u16* __restrict__ bP2,
    int npass, int K, int m0, u16* SM, int tid, f32x4 (&acc)[4][4]) {
  const int lane = tid & 63;
  const int w = tid >> 6;
  const int wm = w >> 1, wn = w & 1;
  const int sRow = tid >> 3, sSlot = tid & 7;  // 32 rows x 8 chunks(16B)
  const int ldsOff = sRow * 64 + sSlot * 8;
  const size_t aOff = (size_t)(m0 + sRow) * K + ((sSlot ^ (sRow & 7)) * 8);
  const size_t bOff = (size_t)sRow * K + ((sSlot ^ (sRow & 7)) * 8);
  const u16* aCur = aP0 + aOff;
  const u16* bCur = bP0 + bOff;
  int sp = 0, sk = 0;  // next tile to stage
  auto stageNext = [&](int b) {
    u16* d = SM + b * 16384 + ldsOff;
    const u16* as = aCur + sk;
    const u16* bs = bCur + sk;
#pragma unroll
    for (int r = 0; r < 4; ++r) {
      gload16(as + (size_t)(r * 32) * K, d + r * 32 * 64);
      gload16(bs + (size_t)(r * 32) * K, d + 8192 + r * 32 * 64);
    }
    sk += 64;
    if (sk == K) {
      sk = 0; ++sp;
      if (sp == 1) { aCur = aP1 + aOff; bCur = bP1 + bOff; }
      else         { aCur = aP2 + aOff; bCur = bP2 + bOff; }
    }
  };

  const int ntiles = npass * (K >> 6);
  stageNext(0);
  int cur = 0;
  for (int ti = 0; ti < ntiles; ++ti) {
    if (ti + 1 < ntiles) {
      stageNext(cur ^ 1);
      asm volatile("s_waitcnt vmcnt(8)\n\ts_barrier" ::: "memory");
    } else {
      asm volatile("s_waitcnt vmcnt(0)\n\ts_barrier" ::: "memory");
    }
    const u16* As = SM + cur * 16384;
    const u16* Bs = As + 8192;
#pragma unroll
    for (int s = 0; s < 2; ++s) {
      const int cAx = s * 4 + (lane >> 4);
      const int colO = (cAx ^ (lane & 7)) * 8;  // T2 swizzled read chunk
      bf16x8 af[4], bfr[4];
#pragma unroll
      for (int t = 0; t < 4; ++t) {
        const int rowA = wm * 64 + t * 16 + (lane & 15);
        af[t] = __builtin_bit_cast(bf16x8, *(const u16x8*)&As[rowA * 64 + colO]);
        const int rowB = wn * 64 + t * 16 + (lane & 15);
        bfr[t] = __builtin_bit_cast(bf16x8, *(const u16x8*)&Bs[rowB * 64 + colO]);
      }
#pragma unroll
      for (int mt = 0; mt < 4; ++mt)
#pragma unroll
        for (int nt = 0; nt < 4; ++nt)
          acc[mt][nt] = __builtin_amdgcn_mfma_f32_16x16x32_bf16(
              af[mt], bfr[nt], acc[mt][nt], 0, 0, 0);
    }
    asm volatile("s_barrier" ::: "memory");
    cur ^= 1;
  }
}

// ---------------------------------------------------------------------------
// head-fused GEMM, launched twice (R6 post-mortem: mixing 1-pass and 3-pass
// tiles in one grid desyncs A-panel reuse + overflows per-XCD L2 => 634MB
// FETCH). Head fusion via PRIVATE depth-slice partial stores (no atomics).
//   dispatch 1: colBase=0,    20 col tiles: ord | res | adapter(DF store)
//   dispatch 2: colBase=2560,  8 col tiles: cls 3-pass hi/lo
// ---------------------------------------------------------------------------
__global__ __launch_bounds__(256, 2) void mega_gemm_kernel(
    const u16* __restrict__ xh, const u16* __restrict__ xl,
    const u16* __restrict__ Tall, const u16* __restrict__ Tc1h,
    const u16* __restrict__ Tc1l,
    const float* __restrict__ bo1, const float* __restrict__ br1,
    const float* __restrict__ ba, const float* __restrict__ bc1,
    const float* __restrict__ Wo2, const float* __restrict__ Wr2,
    const float* __restrict__ Wc2,
    float* __restrict__ ordpart, float* __restrict__ respart,
    float* __restrict__ clspart, u16* __restrict__ DF, int colBase) {
  __shared__ __attribute__((aligned(16))) u16 SM[4 * 128 * 64];
  const int tid = threadIdx.x;
  const int lane = tid & 63;
  const int w = tid >> 6;
  const int wm = w >> 1, wn = w & 1;
  // XCD-aware bijective swizzle (nwg % 8 == 0 for both grids)
  const unsigned nwg = gridDim.x * gridDim.y;
  const unsigned wgid = blockIdx.y * gridDim.x + blockIdx.x;
  const unsigned swz = (wgid & 7u) * (nwg >> 3) + (wgid >> 3);
  const int m0 = (int)(swz / gridDim.x) * 128;
  const int n0 = colBase + (int)(swz % gridDim.x) * 128;

  f32x4 acc[4][4] = {};
  if (n0 < NFUSE) {
    const u16* b = Tall + (size_t)n0 * DIM;
    gemm_loop(xh, b, xh, b, xh, b, 1, DIM, m0, SM, tid, acc);
  } else {
    const u16* bh = Tc1h + (size_t)(n0 - NFUSE) * DIM;
    const u16* bl = Tc1l + (size_t)(n0 - NFUSE) * DIM;
    gemm_loop(xh, bh, xh, bl, xl, bh, 3, DIM, m0, SM, tid, acc);
  }

  const int q = lane >> 4, cl = lane & 15;
  if (n0 < ORDH) {
    const int d = (n0 >> 7) * 2 + wn;  // 0..7
#pragma unroll
    for (int mt = 0; mt < 4; ++mt)
#pragma unroll
      for (int i = 0; i < 4; ++i) {
        const int row = m0 + wm * 64 + mt * 16 + q * 4 + i;
        float s[6] = {0, 0, 0, 0, 0, 0};
#pragma unroll
        for (int nt = 0; nt < 4; ++nt) {
          const int col = n0 + wn * 64 + nt * 16 + cl;
          float v = acc[mt][nt][i] + bo1[col];
          v = v > 0.f ? v : 0.f;
          const float* wr = Wo2 + col * 6;
#pragma unroll
          for (int n = 0; n < 6; ++n) s[n] += v * wr[n];
        }
#pragma unroll
        for (int n = 0; n < 6; ++n) {
          s[n] += __shfl_xor(s[n], 1);
          s[n] += __shfl_xor(s[n], 2);
          s[n] += __shfl_xor(s[n], 4);
          s[n] += __shfl_xor(s[n], 8);
        }
        if (cl == 0)
#pragma unroll
          for (int n = 0; n < 6; ++n)
            ordpart[(size_t)(d * 6 + n) * B_ROWS + row] = s[n];
      }
  } else if (n0 < ORDH + DIM) {
    const int d = ((n0 - ORDH) >> 7) * 2 + wn;  // 0..15
#pragma unroll
    for (int mt = 0; mt < 4; ++mt)
#pragma unroll
      for (int i = 0; i < 4; ++i) {
        const int row = m0 + wm * 64 + mt * 16 + q * 4 + i;
        float s = 0.f;
#pragma unroll
        for (int nt = 0; nt < 4; ++nt) {
          const int hc = n0 - ORDH + wn * 64 + nt * 16 + cl;
          float v = acc[mt][nt][i] + br1[hc];
          v = v > 0.f ? v : 0.f;
          s += v * Wr2[hc];
        }
        s += __shfl_xor(s, 1);
        s += __shfl_xor(s, 2);
        s += __shfl_xor(s, 4);
        s += __shfl_xor(s, 8);
        if (cl == 0) respart[(size_t)d * B_ROWS + row] = s;
      }
  } else if (n0 < NFUSE) {
    // adapter: materialize DF (experts consume it)
#pragma unroll
    for (int nt = 0; nt < 4; ++nt) {
      const int col = n0 - (ORDH + DIM) + wn * 64 + nt * 16 + cl;
      const float bv = ba[col];
#pragma unroll
      for (int mt = 0; mt < 4; ++mt)
#pragma unroll
        for (int i = 0; i < 4; ++i) {
          const int row = m0 + wm * 64 + mt * 16 + q * 4 + i;
          float v = acc[mt][nt][i] + bv;
          v = v > 0.f ? v : 0.f;
          DF[(size_t)row * DIM + col] = f2bf(v);
        }
    }
  } else {
    const int d = ((n0 - NFUSE) >> 7) * 2 + wn;  // 0..15
#pragma unroll
    for (int mt = 0; mt < 4; ++mt)
#pragma unroll
      for (int i = 0; i < 4; ++i) {
        const int row = m0 + wm * 64 + mt * 16 + q * 4 + i;
        float s[7] = {0, 0, 0, 0, 0, 0, 0};
#pragma unroll
        for (int nt = 0; nt < 4; ++nt) {
          const int hc = n0 - NFUSE + wn * 64 + nt * 16 + cl;
          float v = acc[mt][nt][i] + bc1[hc];
          v = v > 0.f ? v : 0.f;
          const float* wr = Wc2 + hc * 7;
#pragma unroll
          for (int n = 0; n < 7; ++n) s[n] += v * wr[n];
        }
#pragma unroll
        for (int n = 0; n < 7; ++n) {
          s[n] += __shfl_xor(s[n], 1);
          s[n] += __shfl_xor(s[n], 2);
          s[n] += __shfl_xor(s[n], 4);
          s[n] += __shfl_xor(s[n], 8);
        }
        if (cl == 0)
#pragma unroll
          for (int n = 0; n < 7; ++n)
            clspart[(size_t)(d * 7 + n) * B_ROWS + row] = s[n];
      }
  }
}

// expert1 (R6-exact): rows [base+t0, base+cnt[e]), A gathered through perm.
__global__ __launch_bounds__(256, 2) void mgemm_expert1_kernel(
    const u16* __restrict__ Abuf, const u16* __restrict__ Wall,
    const float* __restrict__ biasAll, const int* __restrict__ cnt,
    const int* __restrict__ perm, u16* __restrict__ outH) {
  __shared__ __attribute__((aligned(16))) u16 SM[4 * 128 * 64];
  const int e = blockIdx.z;
  const int myCnt = cnt[e];
  const int t0 = blockIdx.y * 128;
  if (t0 >= myCnt) return;
  int base = 0;
  for (int t = 0; t < NEXP; ++t) base += (t < e) ? cnt[t] : 0;
  const int m0 = base + t0;
  const int mEnd = base + myCnt;
  const u16* Bp = Wall + (size_t)e * DIM * DIM;
  const float* bias = biasAll + (size_t)e * DIM;

  const int tid = threadIdx.x;
  const int lane = tid & 63;
  const int w = tid >> 6;
  const int wm = w >> 1, wn = w & 1;
  const int n0 = blockIdx.x * 128;
  const int sRow = tid >> 3, sSlot = tid & 7;
  const int ldsOff = sRow * 64 + sSlot * 8;
  const int swzC = (sSlot ^ (sRow & 7)) * 8;

  const u16* aSrc[4];
#pragma unroll
  for (int r = 0; r < 4; ++r) {
    int ar = m0 + r * 32 + sRow;
    if (ar > B_ROWS - 1) ar = B_ROWS - 1;
    aSrc[r] = Abuf + (size_t)perm[ar] * DIM + swzC;
  }
  const u16* bSrc = Bp + (size_t)(n0 + sRow) * DIM + swzC;

  int sk = 0;
  auto stageNext = [&](int b) {
    u16* d = SM + b * 16384 + ldsOff;
#pragma unroll
    for (int r = 0; r < 4; ++r)
      gload16(aSrc[r] + sk, d + r * 32 * 64);
#pragma unroll
    for (int r = 0; r < 4; ++r)
      gload16(bSrc + (size_t)(r * 32) * DIM + sk, d + 8192 + r * 32 * 64);
    sk += 64;
  };

  f32x4 acc[4][4] = {};
  const int ntiles = DIM >> 6;
  stageNext(0);
  int cur = 0;
  for (int ti = 0; ti < ntiles; ++ti) {
    if (ti + 1 < ntiles) {
      stageNext(cur ^ 1);
      asm volatile("s_waitcnt vmcnt(8)\n\ts_barrier" ::: "memory");
    } else {
      asm volatile("s_waitcnt vmcnt(0)\n\ts_barrier" ::: "memory");
    }
    const u16* As = SM + cur * 16384;
    const u16* Bs = As + 8192;
#pragma unroll
    for (int s = 0; s < 2; ++s) {
      const int cAx = s * 4 + (lane >> 4);
      const int colO = (cAx ^ (lane & 7)) * 8;
      bf16x8 af[4], bfr[4];
#pragma unroll
      for (int t = 0; t < 4; ++t) {
        const int rowA = wm * 64 + t * 16 + (lane & 15);
        af[t] = __builtin_bit_cast(bf16x8, *(const u16x8*)&As[rowA * 64 + colO]);
        const int rowB = wn * 64 + t * 16 + (lane & 15);
        bfr[t] = __builtin_bit_cast(bf16x8, *(const u16x8*)&Bs[rowB * 64 + colO]);
      }
#pragma unroll
      for (int mt = 0; mt < 4; ++mt)
#pragma unroll
        for (int nt = 0; nt < 4; ++nt)
          acc[mt][nt] = __builtin_amdgcn_mfma_f32_16x16x32_bf16(
              af[mt], bfr[nt], acc[mt][nt], 0, 0, 0);
    }
    asm volatile("s_barrier" ::: "memory");
    cur ^= 1;
  }

  const int q = lane >> 4, cl = lane & 15;
#pragma unroll
  for (int nt = 0; nt < 4; ++nt) {
    const int col = n0 + wn * 64 + nt * 16 + cl;
    const float bv = bias[col];
#pragma unroll
    for (int mt = 0; mt < 4; ++mt) {
#pragma unroll
      for (int i = 0; i < 4; ++i) {
        const int row = m0 + wm * 64 + mt * 16 + q * 4 + i;
        if (row < mEnd) {
          float v = acc[mt][nt][i] + bv;
          v = v > 0.f ? v : 0.f;
          outH[(size_t)row * DIM + col] = f2bf(v);
        }
      }
    }
  }
}

// expert2 (R6-exact): GEMM + fused head_dl via partial-store slices.
__global__ __launch_bounds__(256, 2) void mgemm_expert2_kernel(
    const u16* __restrict__ Abuf, const u16* __restrict__ Wall,
    const float* __restrict__ biasAll, const int* __restrict__ cnt,
    const float* __restrict__ We3, float* __restrict__ dlpart) {
  __shared__ __attribute__((aligned(16))) u16 SM[4 * 128 * 64];
  const int e = blockIdx.z;
  const int myCnt = cnt[e];
  const int t0 = blockIdx.y * 128;
  if (t0 >= myCnt) return;
  int base = 0;
  for (int t = 0; t < NEXP; ++t) base += (t < e) ? cnt[t] : 0;
  const int m0 = base + t0;
  const int mEnd = base + myCnt;
  const u16* Bp = Wall + (size_t)e * DIM * DIM;
  const float* bias = biasAll + (size_t)e * DIM;
  const float* W3 = We3 + (size_t)e * DIM * 3;

  const int tid = threadIdx.x;
  const int lane = tid & 63;
  const int w = tid >> 6;
  const int wm = w >> 1, wn = w & 1;
  const int n0 = blockIdx.x * 128;
  const int sRow = tid >> 3, sSlot = tid & 7;
  const int ldsOff = sRow * 64 + sSlot * 8;
  const int swzC = (sSlot ^ (sRow & 7)) * 8;

  const u16* aSrc[4];
#pragma unroll
  for (int r = 0; r < 4; ++r) {
    int ar = m0 + r * 32 + sRow;
    if (ar > B_ROWS - 1) ar = B_ROWS - 1;
    aSrc[r] = Abuf + (size_t)ar * DIM + swzC;
  }
  const u16* bSrc = Bp + (size_t)(n0 + sRow) * DIM + swzC;

  int sk = 0;
  auto stageNext = [&](int b) {
    u16* d = SM + b * 16384 + ldsOff;
#pragma unroll
    for (int r = 0; r < 4; ++r)
      gload16(aSrc[r] + sk, d + r * 32 * 64);
#pragma unroll
    for (int r = 0; r < 4; ++r)
      gload16(bSrc + (size_t)(r * 32) * DIM + sk, d + 8192 + r * 32 * 64);
    sk += 64;
  };

  f32x4 acc[4][4] = {};
  const int ntiles = DIM >> 6;
  stageNext(0);
  int cur = 0;
  for (int ti = 0; ti < ntiles; ++ti) {
    if (ti + 1 < ntiles) {
      stageNext(cur ^ 1);
      asm volatile("s_waitcnt vmcnt(8)\n\ts_barrier" ::: "memory");
    } else {
      asm volatile("s_waitcnt vmcnt(0)\n\ts_barrier" ::: "memory");
    }
    const u16* As = SM + cur * 16384;
    const u16* Bs = As + 8192;
#pragma unroll
    for (int s = 0; s < 2; ++s) {
      const int cAx = s * 4 + (lane >> 4);
      const int colO = (cAx ^ (lane & 7)) * 8;
      bf16x8 af[4], bfr[4];
#pragma unroll
      for (int t = 0; t < 4; ++t) {
        const int rowA = wm * 64 + t * 16 + (lane & 15);
        af[t] = __builtin_bit_cast(bf16x8, *(const u16x8*)&As[rowA * 64 + colO]);
        const int rowB = wn * 64 + t * 16 + (lane & 15);
        bfr[t] = __builtin_bit_cast(bf16x8, *(const u16x8*)&Bs[rowB * 64 + colO]);
      }
#pragma unroll
      for (int mt = 0; mt < 4; ++mt)
#pragma unroll
        for (int nt = 0; nt < 4; ++nt)
          acc[mt][nt] = __builtin_amdgcn_mfma_f32_16x16x32_bf16(
              af[mt], bfr[nt], acc[mt][nt], 0, 0, 0);
    }
    asm volatile("s_barrier" ::: "memory");
    cur ^= 1;
  }

  const int q = lane >> 4, cl = lane & 15;
  const int d = (n0 >> 7) * 2 + wn;  // 0..15
#pragma unroll
  for (int mt = 0; mt < 4; ++mt)
#pragma unroll
    for (int i = 0; i < 4; ++i) {
      const int row = m0 + wm * 64 + mt * 16 + q * 4 + i;
      float s0 = 0.f, s1 = 0.f, s2 = 0.f;
#pragma unroll
      for (int nt = 0; nt < 4; ++nt) {
        const int col = n0 + wn * 64 + nt * 16 + cl;
        float v = acc[mt][nt][i] + bias[col];
        v = v > 0.f ? v : 0.f;
        const float* wr = W3 + col * 3;
        s0 += v * wr[0]; s1 += v * wr[1]; s2 += v * wr[2];
      }
      s0 += __shfl_xor(s0, 1); s0 += __shfl_xor(s0, 2);
      s0 += __shfl_xor(s0, 4); s0 += __shfl_xor(s0, 8);
      s1 += __shfl_xor(s1, 1); s1 += __shfl_xor(s1, 2);
      s1 += __shfl_xor(s1, 4); s1 += __shfl_xor(s1, 8);
      s2 += __shfl_xor(s2, 1); s2 += __shfl_xor(s2, 2);
      s2 += __shfl_xor(s2, 4); s2 += __shfl_xor(s2, 8);
      if (cl == 0 && row < mEnd) {
        dlpart[(size_t)(d * 3 + 0) * B_ROWS + row] = s0;
        dlpart[(size_t)(d * 3 + 1) * B_ROWS + row] = s1;
        dlpart[(size_t)(d * 3 + 2) * B_ROWS + row] = s2;
      }
    }
}

// ---------------------------------------------------------------------------
// finalize: one thread per row; sums depth slices (coalesced reads).
// ---------------------------------------------------------------------------
__global__ __launch_bounds__(256) void finalize_cls_kernel(
    const float* __restrict__ ordpart, const float* __restrict__ bo2,
    const float* __restrict__ respart, const float* __restrict__ br2,
    const float* __restrict__ clspart, const float* __restrict__ bc2,
    float* __restrict__ out, int* __restrict__ size_idx, int* __restrict__ gcnt) {
  __shared__ int lcnt[NEXP];
  const int tid = threadIdx.x;
  if (tid < NEXP) lcnt[tid] = 0;
  __syncthreads();
  const int r = blockIdx.x * 256 + tid;
  float ov[6] = {0, 0, 0, 0, 0, 0};
#pragma unroll
  for (int d = 0; d < 8; ++d)
#pragma unroll
    for (int n = 0; n < 6; ++n) ov[n] += ordpart[(size_t)(d * 6 + n) * B_ROWS + r];
  float rs = 0.f;
#pragma unroll
  for (int d = 0; d < 16; ++d) rs += respart[(size_t)d * B_ROWS + r];
  float lg[7] = {0, 0, 0, 0, 0, 0, 0};
#pragma unroll
  for (int d = 0; d < 16; ++d)
#pragma unroll
    for (int n = 0; n < 7; ++n) lg[n] += clspart[(size_t)(d * 7 + n) * B_ROWS + r];

  float* orow = out + (size_t)r * 24;
#pragma unroll
  for (int n = 0; n < 6; ++n) orow[7 + n] = ov[n] + bo2[n];
  const float resv = 0.35f * tanhf(rs + br2[0]);
  float pb[7];
  float m = -1e30f;
  int ai = 0;
#pragma unroll
  for (int n = 0; n < 7; ++n) {
    lg[n] += bc2[n];
    if (lg[n] > m) { m = lg[n]; ai = n; }  // first max == np.argmax
  }
  float es = 0.f;
#pragma unroll
  for (int n = 0; n < 7; ++n) { pb[n] = expf(lg[n] - m); es += pb[n]; }
  const float inv = 1.f / es;
  float expect = 0.f;
#pragma unroll
  for (int n = 0; n < 7; ++n) { pb[n] *= inv; expect += pb[n] * (n * (1.f / 6.f)); }
  float reg = expect + resv;
  reg = fminf(fmaxf(reg, 0.f), 1.f);
#pragma unroll
  for (int n = 0; n < 7; ++n) orow[n] = lg[n];
  orow[13] = reg;
#pragma unroll
  for (int n = 0; n < 7; ++n) orow[14 + n] = pb[n];
  size_idx[r] = ai;
  atomicAdd(&lcnt[ai], 1);
  __syncthreads();
  if (tid < NEXP && lcnt[tid] > 0) atomicAdd(&gcnt[tid], lcnt[tid]);
}

// scatter: off computed locally from final gcnt; cursor pre-zeroed.
__global__ __launch_bounds__(256) void scatter_kernel(
    const int* __restrict__ size_idx, const int* __restrict__ gcnt,
    int* __restrict__ cursor, int* __restrict__ perm) {
  __shared__ int lcnt[NEXP];
  __shared__ int lbase[NEXP];
  const int tid = threadIdx.x;
  if (tid < NEXP) lcnt[tid] = 0;
  __syncthreads();
  const int r = blockIdx.x * 256 + tid;
  const int e = size_idx[r];
  const int lp = atomicAdd(&lcnt[e], 1);
  __syncthreads();
  if (tid < NEXP && lcnt[tid] > 0) {
    int off = 0;
    for (int t = 0; t < tid; ++t) off += gcnt[t];
    lbase[tid] = off + atomicAdd(&cursor[tid], lcnt[tid]);
  }
  __syncthreads();
  perm[lbase[e] + lp] = r;
}

__global__ __launch_bounds__(256) void finalize_dl_kernel(
    const float* __restrict__ dlpart, const float* __restrict__ be3,
    const int* __restrict__ gcnt, const int* __restrict__ perm,
    float* __restrict__ out) {
  const int i = blockIdx.x * 256 + threadIdx.x;
  int e = 0, a = 0;
#pragma unroll
  for (int t = 0; t < NEXP - 1; ++t) {
    a += gcnt[t];
    if (i >= a) e = t + 1;
  }
  float s[3] = {0, 0, 0};
#pragma unroll
  for (int d = 0; d < 16; ++d)
#pragma unroll
    for (int c = 0; c < 3; ++c) s[c] += dlpart[(size_t)(d * 3 + c) * B_ROWS + i];
  const int r = perm[i];
  float* orow = out + (size_t)r * 24;
#pragma unroll
  for (int c = 0; c < 3; ++c) orow[21 + c] = s[c] + be3[e * 3 + c];
}

// ---------------------------------------------------------------------------
extern "C" void kernel_launch(void* const* d_in, const int* in_sizes, int n_in,
                              void* d_out, int out_size, void* d_ws, size_t ws_size,
                              hipStream_t stream) {
  (void)in_sizes; (void)n_in; (void)out_size; (void)ws_size;
  const float* x   = (const float*)d_in[0];
  const float* Wc1 = (const float*)d_in[1];
  const float* bc1 = (const float*)d_in[2];
  const float* Wc2 = (const float*)d_in[3];
  const float* bc2 = (const float*)d_in[4];
  const float* Wo1 = (const float*)d_in[5];
  const float* bo1 = (const float*)d_in[6];
  const float* Wo2 = (const float*)d_in[7];
  const float* bo2 = (const float*)d_in[8];
  const float* Wr1 = (const float*)d_in[9];
  const float* br1 = (const float*)d_in[10];
  const float* Wr2 = (const float*)d_in[11];
  const float* br2 = (const float*)d_in[12];
  const float* Wa  = (const float*)d_in[13];
  const float* ba  = (const float*)d_in[14];
  const float* We1 = (const float*)d_in[15];
  const float* be1 = (const float*)d_in[16];
  const float* We2 = (const float*)d_in[17];
  const float* be2 = (const float*)d_in[18];
  const float* We3 = (const float*)d_in[19];
  const float* be3 = (const float*)d_in[20];
  float* out = (float*)d_out;  // fp32 output

  char* p = (char*)d_ws;
  auto carve = [&](size_t bytes) {
    char* r = p;
    p += (bytes + 255) & ~(size_t)255;
    return r;
  };
  u16* xh   = (u16*)carve((size_t)B_ROWS * DIM * 2);       // 32MB
  u16* xl   = (u16*)carve((size_t)B_ROWS * DIM * 2);       // 32MB
  u16* Tc1h = (u16*)carve((size_t)DIM * DIM * 2);          // 2MB
  u16* Tc1l = (u16*)carve((size_t)DIM * DIM * 2);          // 2MB
  u16* Tall = (u16*)carve((size_t)NFUSE * DIM * 2);        // 5MB: To1|Tr1|Ta
  u16* Te1  = (u16*)carve((size_t)NEXP * DIM * DIM * 2);   // 14MB
  u16* Te2  = (u16*)carve((size_t)NEXP * DIM * DIM * 2);   // 14MB
  u16* DF   = (u16*)carve((size_t)B_ROWS * DIM * 2);       // 32MB (adapter out)
  float* ordpart = (float*)carve((size_t)8 * 6 * B_ROWS * 4);   // 3MB
  float* respart = (float*)carve((size_t)16 * B_ROWS * 4);      // 1MB
  float* clspart = (float*)carve((size_t)16 * 7 * B_ROWS * 4);  // 7.3MB
  float* dlpart  = (float*)carve((size_t)16 * 3 * B_ROWS * 4);  // 3MB
  int* size_idx = (int*)carve((size_t)B_ROWS * 4);
  int* perm   = (int*)carve((size_t)B_ROWS * 4);
  int* gcnt   = (int*)carve(256);
  int* cursor = (int*)carve(256);
  // aliases over dead intervals (stream-ordered):
  u16* H1p = xl;  // xl dead after cls dispatch (pass 3)
  u16* To1 = Tall;                               // fused B rows [0,512)
  u16* Tr1 = Tall + (size_t)ORDH * DIM;          // rows [512,1536)
  u16* Ta  = Tall + (size_t)(ORDH + DIM) * DIM;  // rows [1536,2560)

  dim3 blk(256);
  convert_x_kernel<<<dim3(B_ROWS * DIM / 4 / 256), blk, 0, stream>>>(
      (const float4*)x, (ushort4*)xh, (ushort4*)xl, gcnt, cursor);
  transpose_all_kernel<<<dim3(17920), blk, 0, stream>>>(
      Wc1, Tc1h, Tc1l, Wo1, To1, Wr1, Tr1, Wa, Ta, We1, Te1, We2, Te2);

  // dispatch 1: ord+res+adapter hidden (1-pass), heads fused via partials
  mega_gemm_kernel<<<dim3(NFUSE / 128, B_ROWS / 128), blk, 0, stream>>>(
      xh, xl, Tall, Tc1h, Tc1l, bo1, br1, ba, bc1, Wo2, Wr2, Wc2,
      ordpart, respart, clspart, DF, 0);
  // dispatch 2: cls hidden (3-pass hi/lo), head fused via partials
  mega_gemm_kernel<<<dim3(8, B_ROWS / 128), blk, 0, stream>>>(
      xh, xl, Tall, Tc1h, Tc1l, bo1, br1, ba, bc1, Wo2, Wr2, Wc2,
      ordpart, respart, clspart, DF, NFUSE);
  finalize_cls_kernel<<<dim3(B_ROWS / 256), blk, 0, stream>>>(
      ordpart, bo2, respart, br2, clspart, bc2, out, size_idx, gcnt);
  scatter_kernel<<<dim3(B_ROWS / 256), blk, 0, stream>>>(size_idx, gcnt, cursor, perm);

  // experts (R6-exact 3-D grids): expert1 gathers via perm; expert2 fuses dl
  mgemm_expert1_kernel<<<dim3(DIM / 128, B_ROWS / 128, NEXP), blk, 0, stream>>>(
      DF, Te1, be1, gcnt, perm, H1p);
  mgemm_expert2_kernel<<<dim3(DIM / 128, B_ROWS / 128, NEXP), blk, 0, stream>>>(
      H1p, Te2, be2, gcnt, We3, dlpart);
  finalize_dl_kernel<<<dim3(B_ROWS / 256), blk, 0, stream>>>(
      dlpart, be3, gcnt, perm, out);
}